// Round 1
// baseline (719.834 us; speedup 1.0000x reference)
//
#include <hip/hip_runtime.h>

// ---------------- constants ----------------
#define Bn 4
#define Tn 2048
#define Cn 1024
#define Hn 16
#define Dn 64
#define Mr (Bn*Tn)          // 8192 rows

typedef _Float16 half8 __attribute__((ext_vector_type(8)));
typedef _Float16 half4v __attribute__((ext_vector_type(4)));
typedef float f32x4 __attribute__((ext_vector_type(4)));

__device__ __forceinline__ void g2l16(const void* g, void* l) {
  __builtin_amdgcn_global_load_lds((__attribute__((address_space(1))) void*)g,
                                   (__attribute__((address_space(3))) void*)l, 16, 0, 0);
}

// ---------------- transpose f32 -> f16 (B^T weight prep) ----------------
// out[c][r] = in[r][c]; in is [R][C]; grid (C/32, R/32, Z); block (32,8)
__global__ __launch_bounds__(256) void transpose_f32_f16(const float* __restrict__ in,
                                                         _Float16* __restrict__ out,
                                                         int R, int C) {
  __shared__ float tile[32][33];
  const size_t zoff = (size_t)blockIdx.z * R * C;
  in += zoff; out += zoff;
  const int c0 = blockIdx.x * 32, r0 = blockIdx.y * 32;
  const int tx = threadIdx.x, ty = threadIdx.y;
#pragma unroll
  for (int i = 0; i < 4; ++i)
    tile[ty + i*8][tx] = in[(size_t)(r0 + ty + i*8) * C + c0 + tx];
  __syncthreads();
#pragma unroll
  for (int i = 0; i < 4; ++i)
    out[(size_t)(c0 + ty + i*8) * R + r0 + tx] = (_Float16)tile[tx][ty + i*8];
}

// ---------------- LayerNorm row kernel: f32 in -> f16 out ----------------
__global__ __launch_bounds__(256) void ln_row(const float* __restrict__ x,
                                              const float* __restrict__ g,
                                              const float* __restrict__ bta,
                                              _Float16* __restrict__ out) {
  const int row = blockIdx.x;
  const float4 v = ((const float4*)(x + (size_t)row * Cn))[threadIdx.x];
  float s  = v.x + v.y + v.z + v.w;
  float ss = v.x*v.x + v.y*v.y + v.z*v.z + v.w*v.w;
#pragma unroll
  for (int m = 1; m < 64; m <<= 1) { s += __shfl_xor(s, m); ss += __shfl_xor(ss, m); }
  __shared__ float red[8];
  const int wave = threadIdx.x >> 6, lane = threadIdx.x & 63;
  if (lane == 0) { red[wave] = s; red[4 + wave] = ss; }
  __syncthreads();
  s  = red[0] + red[1] + red[2] + red[3];
  ss = red[4] + red[5] + red[6] + red[7];
  const float mean = s * (1.0f/Cn);
  const float var  = ss * (1.0f/Cn) - mean*mean;
  const float rstd = rsqrtf(var + 1e-6f);
  const int c = threadIdx.x * 4;
  const float4 gg = ((const float4*)g)[threadIdx.x];
  const float4 bb = ((const float4*)bta)[threadIdx.x];
  half4v o;
  o[0] = (_Float16)((v.x - mean) * rstd * gg.x + bb.x);
  o[1] = (_Float16)((v.y - mean) * rstd * gg.y + bb.y);
  o[2] = (_Float16)((v.z - mean) * rstd * gg.z + bb.z);
  o[3] = (_Float16)((v.w - mean) * rstd * gg.w + bb.w);
  *((half4v*)(out + (size_t)row * Cn + c)) = o;
}

// ---------------- GEMM: C[M,N] = A[M,K] * Bt[N,K]^T, m97 structure ----------------
enum { EPI_QK = 0, EPI_V = 1, EPI_PROJ = 2, EPI_FF1 = 3, EPI_FF2 = 4 };

template<int EPI>
__global__ __launch_bounds__(256) void gemm_bt(const _Float16* __restrict__ A,
                                               const _Float16* __restrict__ Bt,
                                               void* __restrict__ outp,
                                               const float* __restrict__ bias,
                                               const float* __restrict__ resid,
                                               int M, int N, int K) {
  __shared__ __align__(16) _Float16 As[128*64];
  __shared__ __align__(16) _Float16 Bs[128*64];
  const int tid = threadIdx.x, wave = tid >> 6, lane = tid & 63;
  const int lr = lane & 15, lg = lane >> 4;
  const int brow = blockIdx.y * 128, bcol = blockIdx.x * 128;
  const int wrow = (wave >> 1) * 64, wcol = (wave & 1) * 64;
  f32x4 acc[4][4] = {};

  for (int kt = 0; kt < K; kt += 64) {
#pragma unroll
    for (int i = 0; i < 4; ++i) {
      const int chunk = i*4 + wave;          // 16 chunks of 1KB per 128x64 tile
      const int e = chunk*512 + lane*8;      // element index
      const int rr = e >> 6, cc = e & 63;
      g2l16(A  + (size_t)(brow + rr)*K + kt + cc, As + chunk*512);
      g2l16(Bt + (size_t)(bcol + rr)*K + kt + cc, Bs + chunk*512);
    }
    __syncthreads();
#pragma unroll
    for (int kk = 0; kk < 64; kk += 32) {
      half8 af[4], bfr[4];
#pragma unroll
      for (int i = 0; i < 4; ++i) af[i]  = *(const half8*)(As + (wrow + i*16 + lr)*64 + kk + lg*8);
#pragma unroll
      for (int j = 0; j < 4; ++j) bfr[j] = *(const half8*)(Bs + (wcol + j*16 + lr)*64 + kk + lg*8);
#pragma unroll
      for (int i = 0; i < 4; ++i)
#pragma unroll
        for (int j = 0; j < 4; ++j)
          acc[i][j] = __builtin_amdgcn_mfma_f32_16x16x32_f16(af[i], bfr[j], acc[i][j], 0, 0, 0);
    }
    __syncthreads();
  }

  // C/D frag: col = lane&15, row = (lane>>4)*4 + r
  const int r0 = brow + wrow + lg*4;
  const int c0 = bcol + wcol + lr;
#pragma unroll
  for (int i = 0; i < 4; ++i) {
#pragma unroll
    for (int j = 0; j < 4; ++j) {
      const int col = c0 + j*16;
#pragma unroll
      for (int r = 0; r < 4; ++r) {
        const int row = r0 + i*16 + r;
        const float v = acc[i][j][r];
        if constexpr (EPI == EPI_QK) {
          // out[b][h][t][d], b=row>>11, t=row&2047, h=col>>6, d=col&63
          ((_Float16*)outp)[(((size_t)(row >> 11) * Hn + (col >> 6)) * Tn + (row & 2047)) * Dn + (col & 63)] = (_Float16)v;
        } else if constexpr (EPI == EPI_V) {
          // out[b][h][d][t]  (pre-transposed V for attention PV B-operand)
          ((_Float16*)outp)[(((size_t)(row >> 11) * Hn + (col >> 6)) * Dn + (col & 63)) * Tn + (row & 2047)] = (_Float16)v;
        } else if constexpr (EPI == EPI_PROJ || EPI == EPI_FF2) {
          ((float*)outp)[(size_t)row * N + col] = v + bias[col] + resid[(size_t)row * N + col];
        } else if constexpr (EPI == EPI_FF1) {
          const float t = v + bias[col];
          ((_Float16*)outp)[(size_t)row * N + col] = (_Float16)(t > 0.f ? t : 0.f);
        }
      }
    }
  }
}

// ---------------- Flash attention (causal), QBLK=128, KVBLK=64 ----------------
// q,k: [b][h][t][d] f16; vt: [b][h][d][t] f16; out: [b*T][C] f16 (concat heads)
__global__ __launch_bounds__(256) void attn_kernel(const _Float16* __restrict__ q,
                                                   const _Float16* __restrict__ k,
                                                   const _Float16* __restrict__ vt,
                                                   _Float16* __restrict__ out) {
  const int qt = (int)(gridDim.x - 1 - blockIdx.x) * 128;  // heavy blocks dispatch first
  const int h = blockIdx.y, b = blockIdx.z;
  const int tid = threadIdx.x, wave = tid >> 6, lane = tid & 63;
  const int lr = lane & 15, lg = lane >> 4;
  const size_t bh = (size_t)b * Hn + h;
  const _Float16* qg = q  + bh * (Tn * Dn);
  const _Float16* kg = k  + bh * (Tn * Dn);
  const _Float16* vg = vt + bh * (Dn * Tn);

  __shared__ __align__(16) _Float16 Ks[64*64];
  __shared__ __align__(16) _Float16 Vs[64*64];
  __shared__ __align__(16) _Float16 Ps[4][32*64];

  // Q fragments in registers: wave handles rows [qt+wave*32, +32)
  half8 qf[2][2];
#pragma unroll
  for (int i = 0; i < 2; ++i)
#pragma unroll
    for (int dh = 0; dh < 2; ++dh)
      qf[i][dh] = *(const half8*)(qg + (size_t)(qt + wave*32 + i*16 + lr)*Dn + dh*32 + lg*8);

  f32x4 oacc[2][4] = {};
  float mrow[2][4], lsum[2][4];
#pragma unroll
  for (int qi = 0; qi < 2; ++qi)
#pragma unroll
    for (int r = 0; r < 4; ++r) { mrow[qi][r] = -__builtin_inff(); lsum[qi][r] = 0.f; }

  const int qmax = qt + wave*32 + 31;

  for (int kvt = 0; kvt < qt + 128; kvt += 64) {
#pragma unroll
    for (int i = 0; i < 2; ++i) {
      const int chunk = i*4 + wave;          // 8 chunks of 1KB per 64x64 tile
      const int e = chunk*512 + lane*8;
      const int rr = e >> 6, cc = e & 63;
      g2l16(kg + (size_t)(kvt + rr)*Dn + cc, Ks + chunk*512);
      g2l16(vg + (size_t)rr*Tn + kvt + cc,   Vs + chunk*512);
    }
    __syncthreads();

    if (kvt <= qmax) {
      // S = Q K^T  (B-operand: col=lane&15 -> kv, k=(lane>>4)*8 -> d)
      half8 kb[4][2];
#pragma unroll
      for (int kv = 0; kv < 4; ++kv)
#pragma unroll
        for (int dh = 0; dh < 2; ++dh)
          kb[kv][dh] = *(const half8*)(Ks + (kv*16 + lr)*64 + dh*32 + lg*8);
      f32x4 sv[2][4];
#pragma unroll
      for (int qi = 0; qi < 2; ++qi)
#pragma unroll
        for (int kv = 0; kv < 4; ++kv) {
          f32x4 t = {0.f, 0.f, 0.f, 0.f};
          t = __builtin_amdgcn_mfma_f32_16x16x32_f16(qf[qi][0], kb[kv][0], t, 0, 0, 0);
          t = __builtin_amdgcn_mfma_f32_16x16x32_f16(qf[qi][1], kb[kv][1], t, 0, 0, 0);
          sv[qi][kv] = t;
        }
      // mask (then-scale semantics match reference: masked stay -inf)
      const int qrow0 = qt + wave*32 + lg*4;
#pragma unroll
      for (int qi = 0; qi < 2; ++qi)
#pragma unroll
        for (int kv = 0; kv < 4; ++kv)
#pragma unroll
          for (int r = 0; r < 4; ++r) {
            const int qrow = qrow0 + qi*16 + r;
            const int kcol = kvt + kv*16 + lr;
            const float val = sv[qi][kv][r] * 0.03125f;   // C^-0.5 = 1/32
            sv[qi][kv][r] = (kcol > qrow) ? -__builtin_inff() : val;
          }
      // online softmax
#pragma unroll
      for (int qi = 0; qi < 2; ++qi) {
        float tm[4], al[4], mn[4], ps[4];
#pragma unroll
        for (int r = 0; r < 4; ++r)
          tm[r] = fmaxf(fmaxf(sv[qi][0][r], sv[qi][1][r]), fmaxf(sv[qi][2][r], sv[qi][3][r]));
#pragma unroll
        for (int m = 1; m < 16; m <<= 1)
#pragma unroll
          for (int r = 0; r < 4; ++r)
            tm[r] = fmaxf(tm[r], __shfl_xor(tm[r], m));
#pragma unroll
        for (int r = 0; r < 4; ++r) {
          mn[r] = fmaxf(mrow[qi][r], tm[r]);
          al[r] = __expf(mrow[qi][r] - mn[r]);   // mrow finite after first tile; 0 if -inf
          mrow[qi][r] = mn[r];
          ps[r] = 0.f;
        }
#pragma unroll
        for (int kv = 0; kv < 4; ++kv)
#pragma unroll
          for (int r = 0; r < 4; ++r) {
            const float p = __expf(sv[qi][kv][r] - mn[r]);
            ps[r] += p;
            Ps[wave][(qi*16 + lg*4 + r)*64 + kv*16 + lr] = (_Float16)p;
          }
#pragma unroll
        for (int m = 1; m < 16; m <<= 1)
#pragma unroll
          for (int r = 0; r < 4; ++r)
            ps[r] += __shfl_xor(ps[r], m);
#pragma unroll
        for (int r = 0; r < 4; ++r)
          lsum[qi][r] = lsum[qi][r]*al[r] + ps[r];
#pragma unroll
        for (int df = 0; df < 4; ++df)
#pragma unroll
          for (int r = 0; r < 4; ++r)
            oacc[qi][df][r] *= al[r];
      }
      // PV: A = P (row=lane&15 -> q, k -> kv), B = Vt (col=lane&15 -> d, k -> kv)
      half8 vb[4][2];
#pragma unroll
      for (int df = 0; df < 4; ++df)
#pragma unroll
        for (int kh = 0; kh < 2; ++kh)
          vb[df][kh] = *(const half8*)(Vs + (df*16 + lr)*64 + kh*32 + lg*8);
#pragma unroll
      for (int qi = 0; qi < 2; ++qi) {
        half8 pa[2];
#pragma unroll
        for (int kh = 0; kh < 2; ++kh)
          pa[kh] = *(const half8*)(&Ps[wave][(qi*16 + lr)*64 + kh*32 + lg*8]);
#pragma unroll
        for (int df = 0; df < 4; ++df) {
          oacc[qi][df] = __builtin_amdgcn_mfma_f32_16x16x32_f16(pa[0], vb[df][0], oacc[qi][df], 0, 0, 0);
          oacc[qi][df] = __builtin_amdgcn_mfma_f32_16x16x32_f16(pa[1], vb[df][1], oacc[qi][df], 0, 0, 0);
        }
      }
    }
    __syncthreads();
  }

  // epilogue: out[b*T + row][h*64 + d]
#pragma unroll
  for (int qi = 0; qi < 2; ++qi)
#pragma unroll
    for (int df = 0; df < 4; ++df)
#pragma unroll
      for (int r = 0; r < 4; ++r) {
        const int row = qt + wave*32 + qi*16 + lg*4 + r;
        const int col = h*Dn + df*16 + lr;
        const float o = oacc[qi][df][r] / lsum[qi][r];
        out[((size_t)b*Tn + row)*Cn + col] = (_Float16)o;
      }
}

// ---------------- host launch ----------------
extern "C" void kernel_launch(void* const* d_in, const int* in_sizes, int n_in,
                              void* d_out, int out_size, void* d_ws, size_t ws_size,
                              hipStream_t stream) {
  const float* x      = (const float*)d_in[0];
  const float* wq     = (const float*)d_in[1];
  const float* wk     = (const float*)d_in[2];
  const float* wv     = (const float*)d_in[3];
  const float* w_proj = (const float*)d_in[4];
  const float* b_proj = (const float*)d_in[5];
  const float* w_ff1  = (const float*)d_in[6];
  const float* b_ff1  = (const float*)d_in[7];
  const float* w_ff2  = (const float*)d_in[8];
  const float* b_ff2  = (const float*)d_in[9];
  const float* ln1s   = (const float*)d_in[10];
  const float* ln1b   = (const float*)d_in[11];
  const float* ln2s   = (const float*)d_in[12];
  const float* ln2b   = (const float*)d_in[13];
  float* outp = (float*)d_out;

  char* ws = (char*)d_ws;
  constexpr size_t MB = (size_t)1 << 20;
  _Float16* Wq_t  = (_Float16*)(ws + 0*MB);    // [1024][1024]
  _Float16* Wk_t  = (_Float16*)(ws + 2*MB);
  _Float16* Wv_t  = (_Float16*)(ws + 4*MB);
  _Float16* Wp_t  = (_Float16*)(ws + 6*MB);
  _Float16* Wf1_t = (_Float16*)(ws + 8*MB);    // [4096][1024]
  _Float16* Wf2_t = (_Float16*)(ws + 16*MB);   // [1024][4096]
  _Float16* xn    = (_Float16*)(ws + 24*MB);   // [8192][1024]; reused as attn_out
  _Float16* attn_o= (_Float16*)(ws + 24*MB);
  _Float16* qbuf  = (_Float16*)(ws + 40*MB);   // [b][h][t][d]
  _Float16* kbuf  = (_Float16*)(ws + 56*MB);
  _Float16* vtbuf = (_Float16*)(ws + 72*MB);   // [b][h][d][t]
  _Float16* hbuf  = (_Float16*)(ws + 40*MB);   // [8192][4096]; overlays q/k/vt (dead by FF1)
  float*    x2    = (float*)   (ws + 104*MB);  // [8192][1024] f32
  _Float16* xn2   = (_Float16*)(ws + 136*MB);  // [8192][1024]

  dim3 tb(32, 8);
  // weight prep (B^T, f16)
  transpose_f32_f16<<<dim3(2, 32, 16), tb, 0, stream>>>(wq, Wq_t, 1024, 64);
  transpose_f32_f16<<<dim3(2, 32, 16), tb, 0, stream>>>(wk, Wk_t, 1024, 64);
  transpose_f32_f16<<<dim3(2, 32, 16), tb, 0, stream>>>(wv, Wv_t, 1024, 64);
  transpose_f32_f16<<<dim3(32, 32, 1), tb, 0, stream>>>(w_proj, Wp_t, 1024, 1024);
  transpose_f32_f16<<<dim3(128, 32, 1), tb, 0, stream>>>(w_ff1, Wf1_t, 1024, 4096);
  transpose_f32_f16<<<dim3(32, 128, 1), tb, 0, stream>>>(w_ff2, Wf2_t, 4096, 1024);

  // LN1
  ln_row<<<Mr, 256, 0, stream>>>(x, ln1s, ln1b, xn);

  // QKV
  gemm_bt<EPI_QK><<<dim3(8, 64), 256, 0, stream>>>(xn, Wq_t, qbuf, nullptr, nullptr, Mr, Cn, Cn);
  gemm_bt<EPI_QK><<<dim3(8, 64), 256, 0, stream>>>(xn, Wk_t, kbuf, nullptr, nullptr, Mr, Cn, Cn);
  gemm_bt<EPI_V ><<<dim3(8, 64), 256, 0, stream>>>(xn, Wv_t, vtbuf, nullptr, nullptr, Mr, Cn, Cn);

  // attention
  attn_kernel<<<dim3(Tn/128, Hn, Bn), 256, 0, stream>>>(qbuf, kbuf, vtbuf, attn_o);

  // proj + residual
  gemm_bt<EPI_PROJ><<<dim3(8, 64), 256, 0, stream>>>(attn_o, Wp_t, x2, b_proj, x, Mr, Cn, Cn);

  // LN2
  ln_row<<<Mr, 256, 0, stream>>>(x2, ln2s, ln2b, xn2);

  // FFN
  gemm_bt<EPI_FF1><<<dim3(32, 64), 256, 0, stream>>>(xn2, Wf1_t, hbuf, b_ff1, nullptr, Mr, 4*Cn, Cn);
  gemm_bt<EPI_FF2><<<dim3(8, 64), 256, 0, stream>>>(hbuf, Wf2_t, outp, b_ff2, x2, Mr, Cn, 4*Cn);
}

// Round 2
// 663.585 us; speedup vs baseline: 1.0848x; 1.0848x over previous
//
#include <hip/hip_runtime.h>

// ---------------- constants ----------------
#define Bn 4
#define Tn 2048
#define Cn 1024
#define Hn 16
#define Dn 64
#define Mr (Bn*Tn)          // 8192 rows

typedef _Float16 half8 __attribute__((ext_vector_type(8)));
typedef _Float16 half4v __attribute__((ext_vector_type(4)));
typedef float f32x4 __attribute__((ext_vector_type(4)));
typedef unsigned u32x4 __attribute__((ext_vector_type(4)));

__device__ __forceinline__ void g2l16(const void* g, void* l) {
  __builtin_amdgcn_global_load_lds((__attribute__((address_space(1))) void*)g,
                                   (__attribute__((address_space(3))) void*)l, 16, 0, 0);
}

// ---------------- transpose f32 -> f16 (B^T weight prep) ----------------
__global__ __launch_bounds__(256) void transpose_f32_f16(const float* __restrict__ in,
                                                         _Float16* __restrict__ out,
                                                         int R, int C) {
  __shared__ float tile[32][33];
  const size_t zoff = (size_t)blockIdx.z * R * C;
  in += zoff; out += zoff;
  const int c0 = blockIdx.x * 32, r0 = blockIdx.y * 32;
  const int tx = threadIdx.x, ty = threadIdx.y;
#pragma unroll
  for (int i = 0; i < 4; ++i)
    tile[ty + i*8][tx] = in[(size_t)(r0 + ty + i*8) * C + c0 + tx];
  __syncthreads();
#pragma unroll
  for (int i = 0; i < 4; ++i)
    out[(size_t)(c0 + ty + i*8) * R + r0 + tx] = (_Float16)tile[tx][ty + i*8];
}

// ---------------- LayerNorm row kernel: f32 in -> f16 out ----------------
__global__ __launch_bounds__(256) void ln_row(const float* __restrict__ x,
                                              const float* __restrict__ g,
                                              const float* __restrict__ bta,
                                              _Float16* __restrict__ out) {
  const int row = blockIdx.x;
  const float4 v = ((const float4*)(x + (size_t)row * Cn))[threadIdx.x];
  float s  = v.x + v.y + v.z + v.w;
  float ss = v.x*v.x + v.y*v.y + v.z*v.z + v.w*v.w;
#pragma unroll
  for (int m = 1; m < 64; m <<= 1) { s += __shfl_xor(s, m); ss += __shfl_xor(ss, m); }
  __shared__ float red[8];
  const int wave = threadIdx.x >> 6, lane = threadIdx.x & 63;
  if (lane == 0) { red[wave] = s; red[4 + wave] = ss; }
  __syncthreads();
  s  = red[0] + red[1] + red[2] + red[3];
  ss = red[4] + red[5] + red[6] + red[7];
  const float mean = s * (1.0f/Cn);
  const float var  = ss * (1.0f/Cn) - mean*mean;
  const float rstd = rsqrtf(var + 1e-6f);
  const int c = threadIdx.x * 4;
  const float4 gg = ((const float4*)g)[threadIdx.x];
  const float4 bb = ((const float4*)bta)[threadIdx.x];
  half4v o;
  o[0] = (_Float16)((v.x - mean) * rstd * gg.x + bb.x);
  o[1] = (_Float16)((v.y - mean) * rstd * gg.y + bb.y);
  o[2] = (_Float16)((v.z - mean) * rstd * gg.z + bb.z);
  o[3] = (_Float16)((v.w - mean) * rstd * gg.w + bb.w);
  *((half4v*)(out + (size_t)row * Cn + c)) = o;
}

// ---------------- GEMM: C[M,N] = A[M,K] * Bt[N,K]^T, m97 structure ----------------
enum { EPI_QK = 0, EPI_V = 1, EPI_PROJ = 2, EPI_FF1 = 3, EPI_FF2 = 4 };

template<int EPI>
__global__ __launch_bounds__(256) void gemm_bt(const _Float16* __restrict__ A,
                                               const _Float16* __restrict__ Bt,
                                               void* __restrict__ outp,
                                               const float* __restrict__ bias,
                                               const float* __restrict__ resid,
                                               int M, int N, int K) {
  __shared__ __align__(16) _Float16 As[128*64];
  __shared__ __align__(16) _Float16 Bs[128*64];
  const int tid = threadIdx.x, wave = tid >> 6, lane = tid & 63;
  const int lr = lane & 15, lg = lane >> 4;
  const int brow = blockIdx.y * 128, bcol = blockIdx.x * 128;
  const int wrow = (wave >> 1) * 64, wcol = (wave & 1) * 64;
  f32x4 acc[4][4] = {};

  for (int kt = 0; kt < K; kt += 64) {
#pragma unroll
    for (int i = 0; i < 4; ++i) {
      const int chunk = i*4 + wave;          // 16 chunks of 1KB per 128x64 tile
      const int e = chunk*512 + lane*8;      // element index
      const int rr = e >> 6, cc = e & 63;
      g2l16(A  + (size_t)(brow + rr)*K + kt + cc, As + chunk*512);
      g2l16(Bt + (size_t)(bcol + rr)*K + kt + cc, Bs + chunk*512);
    }
    __syncthreads();
#pragma unroll
    for (int kk = 0; kk < 64; kk += 32) {
      half8 af[4], bfr[4];
#pragma unroll
      for (int i = 0; i < 4; ++i) af[i]  = *(const half8*)(As + (wrow + i*16 + lr)*64 + kk + lg*8);
#pragma unroll
      for (int j = 0; j < 4; ++j) bfr[j] = *(const half8*)(Bs + (wcol + j*16 + lr)*64 + kk + lg*8);
#pragma unroll
      for (int i = 0; i < 4; ++i)
#pragma unroll
        for (int j = 0; j < 4; ++j)
          acc[i][j] = __builtin_amdgcn_mfma_f32_16x16x32_f16(af[i], bfr[j], acc[i][j], 0, 0, 0);
    }
    __syncthreads();
  }

  // C/D frag: col = lane&15, row = (lane>>4)*4 + r
  const int r0 = brow + wrow + lg*4;
  const int c0 = bcol + wcol + lr;
#pragma unroll
  for (int i = 0; i < 4; ++i) {
#pragma unroll
    for (int j = 0; j < 4; ++j) {
      const int col = c0 + j*16;
#pragma unroll
      for (int r = 0; r < 4; ++r) {
        const int row = r0 + i*16 + r;
        const float v = acc[i][j][r];
        if constexpr (EPI == EPI_QK) {
          ((_Float16*)outp)[(((size_t)(row >> 11) * Hn + (col >> 6)) * Tn + (row & 2047)) * Dn + (col & 63)] = (_Float16)v;
        } else if constexpr (EPI == EPI_V) {
          ((_Float16*)outp)[(((size_t)(row >> 11) * Hn + (col >> 6)) * Dn + (col & 63)) * Tn + (row & 2047)] = (_Float16)v;
        } else if constexpr (EPI == EPI_PROJ || EPI == EPI_FF2) {
          ((float*)outp)[(size_t)row * N + col] = v + bias[col] + resid[(size_t)row * N + col];
        } else if constexpr (EPI == EPI_FF1) {
          const float t = v + bias[col];
          ((_Float16*)outp)[(size_t)row * N + col] = (_Float16)(t > 0.f ? t : 0.f);
        }
      }
    }
  }
}

// ---------------- Flash attention (causal), QBLK=128, KVBLK=64 ----------------
// Swapped-QK^T structure: S^T = mfma(A=K, B=Q) -> each lane owns one q-row.
// In-register softmax; P redistributed to PV A-frags via bpermute (no P LDS).
// K/V tiles double-buffered in swizzled LDS (chunk ^= row&7 on 16B chunks).
// q,k: [b][h][t][d] f16; vt: [b][h][d][t] f16; out: [b*T][C] f16
__global__ __launch_bounds__(256) void attn_kernel(const _Float16* __restrict__ q,
                                                   const _Float16* __restrict__ k,
                                                   const _Float16* __restrict__ vt,
                                                   _Float16* __restrict__ out) {
  const int qt = (int)(gridDim.x - 1 - blockIdx.x) * 128;  // heavy blocks dispatch first
  const int h = blockIdx.y, b = blockIdx.z;
  const int tid = threadIdx.x, wave = tid >> 6, lane = tid & 63;
  const int lr = lane & 15, lg = lane >> 4;
  const size_t bh = (size_t)b * Hn + h;
  const _Float16* qg = q  + bh * (Tn * Dn);
  const _Float16* kg = k  + bh * (Tn * Dn);
  const _Float16* vg = vt + bh * (Dn * Tn);

  __shared__ __align__(16) _Float16 Ks[2][64*64];
  __shared__ __align__(16) _Float16 Vs[2][64*64];

  // Q fragments (B-operand): lane holds Q[q=qt+wave*32+qi*16+lr][d=dh*32+lg*8+j]
  half8 qf[2][2];
#pragma unroll
  for (int qi = 0; qi < 2; ++qi)
#pragma unroll
    for (int dh = 0; dh < 2; ++dh)
      qf[qi][dh] = *(const half8*)(qg + (size_t)(qt + wave*32 + qi*16 + lr)*Dn + dh*32 + lg*8);

  f32x4 oacc[2][4] = {};
  float mrow[2] = {-__builtin_inff(), -__builtin_inff()};
  float lsum[2] = {0.f, 0.f};

  const int qmax = qt + wave*32 + 31;
  const int nt = (qt + 128) >> 6;

  // stage one 64x64 K tile + V tile into buffer bufi, swizzled (chunk ^= row&7)
  auto STAGE = [&](int bufi, int t) {
    const int kvt = t * 64;
#pragma unroll
    for (int r = 0; r < 2; ++r) {
      const int g0 = r*256 + wave*64;          // wave-uniform chunk base
      const int g  = g0 + lane;                // this lane's chunk id (0..511)
      const int rr = g >> 3;                   // tile row
      const int cs = (g & 7) ^ (rr & 7);       // inverse-swizzled source chunk
      g2l16(kg + (size_t)(kvt + rr)*Dn + cs*8, &Ks[bufi][g0*8]);
      g2l16(vg + (size_t)rr*Tn + kvt + cs*8,   &Vs[bufi][g0*8]);
    }
  };

  STAGE(0, 0);
  __syncthreads();

  for (int t = 0; t < nt; ++t) {
    const int kvt = t * 64;
    if (t + 1 < nt) STAGE((t + 1) & 1, t + 1);   // prefetch next tile (overlaps compute)

    if (kvt <= qmax) {
      const _Float16* KS = Ks[t & 1];
      const _Float16* VS = Vs[t & 1];
      // K fragments (A-operand): row = 16f+lr, swizzled chunk = (4dh+lg)^(lr&7)
      half8 kb[4][2];
#pragma unroll
      for (int f = 0; f < 4; ++f)
#pragma unroll
        for (int dh = 0; dh < 2; ++dh)
          kb[f][dh] = *(const half8*)(KS + (16*f + lr)*64 + (((4*dh + lg) ^ (lr & 7)) * 8));

#pragma unroll
      for (int qi = 0; qi < 2; ++qi) {
        // S^T frags: lane holds S[q=qrow][kv=kvt+16f+4lg+r]
        f32x4 sv[4];
#pragma unroll
        for (int f = 0; f < 4; ++f) {
          f32x4 tacc = {0.f, 0.f, 0.f, 0.f};
          tacc = __builtin_amdgcn_mfma_f32_16x16x32_f16(kb[f][0], qf[qi][0], tacc, 0, 0, 0);
          tacc = __builtin_amdgcn_mfma_f32_16x16x32_f16(kb[f][1], qf[qi][1], tacc, 0, 0, 0);
          sv[f] = tacc;
        }
        const int qrow = qt + wave*32 + qi*16 + lr;
        // mask then scale (masked stay -inf, matching reference)
#pragma unroll
        for (int f = 0; f < 4; ++f)
#pragma unroll
          for (int r = 0; r < 4; ++r) {
            const int kvv = kvt + 16*f + 4*lg + r;
            sv[f][r] = (kvv > qrow) ? -__builtin_inff() : sv[f][r] * 0.03125f;
          }
        // row max: 15 local fmax + 2 shfl (row lives on 4 lanes lr+16*lg)
        float tm = sv[0][0];
#pragma unroll
        for (int f = 0; f < 4; ++f)
#pragma unroll
          for (int r = 0; r < 4; ++r) tm = fmaxf(tm, sv[f][r]);
        tm = fmaxf(tm, __shfl_xor(tm, 16));
        tm = fmaxf(tm, __shfl_xor(tm, 32));
        const float mn = fmaxf(mrow[qi], tm);
        const float alpha = __expf(mrow[qi] - mn);
        mrow[qi] = mn;
        // exp + row sum
        float ps = 0.f;
#pragma unroll
        for (int f = 0; f < 4; ++f)
#pragma unroll
          for (int r = 0; r < 4; ++r) {
            const float e = __expf(sv[f][r] - mn);
            ps += e;
            sv[f][r] = e;
          }
        ps += __shfl_xor(ps, 16);
        ps += __shfl_xor(ps, 32);
        lsum[qi] = lsum[qi] * alpha + ps;
        // pack P to f16 pairs: ph[f][m] = (p[f][2m], p[f][2m+1])
        unsigned ph[4][2];
#pragma unroll
        for (int f = 0; f < 4; ++f)
#pragma unroll
          for (int m = 0; m < 2; ++m) {
            const unsigned lo = (unsigned)__builtin_bit_cast(unsigned short, (_Float16)sv[f][2*m]);
            const unsigned hi = (unsigned)__builtin_bit_cast(unsigned short, (_Float16)sv[f][2*m + 1]);
            ph[f][m] = lo | (hi << 16);
          }
        // rescale O rows (oacc row q_local = 4lg+r; alpha lives at lane q_local)
        float ab[4];
#pragma unroll
        for (int r = 0; r < 4; ++r) ab[r] = __shfl(alpha, 4*lg + r);
#pragma unroll
        for (int df = 0; df < 4; ++df)
#pragma unroll
          for (int r = 0; r < 4; ++r) oacc[qi][df][r] *= ab[r];
        // redistribute P -> PV A-frags: lane needs P[q=lr][kv=32kh+8lg+j]
        // from src lanes s0=lr+16*(2*(lg&1)) (j0..3), s1=s0+16 (j4..7), reg f=2kh+(lg>>1)
        const int s0 = lr + 16*(2*(lg & 1));
        const int s1 = s0 + 16;
        half8 pa[2];
#pragma unroll
        for (int kh = 0; kh < 2; ++kh) {
          u32x4 w = {0u, 0u, 0u, 0u};
#pragma unroll
          for (int fi = 0; fi < 2; ++fi) {
            const unsigned a0 = __shfl(ph[2*kh + fi][0], s0);
            const unsigned a1 = __shfl(ph[2*kh + fi][1], s0);
            const unsigned a2 = __shfl(ph[2*kh + fi][0], s1);
            const unsigned a3 = __shfl(ph[2*kh + fi][1], s1);
            const bool sel = ((lg >> 1) == fi);
            w[0] = sel ? a0 : w[0];
            w[1] = sel ? a1 : w[1];
            w[2] = sel ? a2 : w[2];
            w[3] = sel ? a3 : w[3];
          }
          pa[kh] = __builtin_bit_cast(half8, w);
        }
        // PV: O[q][d] += P * V ; B-operand from Vt tile, swizzled reads
#pragma unroll
        for (int df = 0; df < 4; ++df) {
          half8 vb0 = *(const half8*)(VS + (16*df + lr)*64 + (((0 + lg) ^ (lr & 7)) * 8));
          half8 vb1 = *(const half8*)(VS + (16*df + lr)*64 + (((4 + lg) ^ (lr & 7)) * 8));
          oacc[qi][df] = __builtin_amdgcn_mfma_f32_16x16x32_f16(pa[0], vb0, oacc[qi][df], 0, 0, 0);
          oacc[qi][df] = __builtin_amdgcn_mfma_f32_16x16x32_f16(pa[1], vb1, oacc[qi][df], 0, 0, 0);
        }
      }
    }
    __syncthreads();
  }

  // epilogue: out[b*T + row][h*64 + d]
#pragma unroll
  for (int qi = 0; qi < 2; ++qi) {
    const float linv = 1.0f / lsum[qi];
    float lb[4];
#pragma unroll
    for (int r = 0; r < 4; ++r) lb[r] = __shfl(linv, 4*lg + r);
#pragma unroll
    for (int df = 0; df < 4; ++df)
#pragma unroll
      for (int r = 0; r < 4; ++r) {
        const int row = qt + wave*32 + qi*16 + 4*lg + r;
        const int col = h*Dn + df*16 + lr;
        out[((size_t)b*Tn + row)*Cn + col] = (_Float16)(oacc[qi][df][r] * lb[r]);
      }
  }
}

// ---------------- host launch ----------------
extern "C" void kernel_launch(void* const* d_in, const int* in_sizes, int n_in,
                              void* d_out, int out_size, void* d_ws, size_t ws_size,
                              hipStream_t stream) {
  const float* x      = (const float*)d_in[0];
  const float* wq     = (const float*)d_in[1];
  const float* wk     = (const float*)d_in[2];
  const float* wv     = (const float*)d_in[3];
  const float* w_proj = (const float*)d_in[4];
  const float* b_proj = (const float*)d_in[5];
  const float* b_ff1  = (const float*)d_in[7];
  const float* w_ff1  = (const float*)d_in[6];
  const float* w_ff2  = (const float*)d_in[8];
  const float* b_ff2  = (const float*)d_in[9];
  const float* ln1s   = (const float*)d_in[10];
  const float* ln1b   = (const float*)d_in[11];
  const float* ln2s   = (const float*)d_in[12];
  const float* ln2b   = (const float*)d_in[13];
  float* outp = (float*)d_out;

  char* ws = (char*)d_ws;
  constexpr size_t MB = (size_t)1 << 20;
  _Float16* Wq_t  = (_Float16*)(ws + 0*MB);    // [1024][1024]
  _Float16* Wk_t  = (_Float16*)(ws + 2*MB);
  _Float16* Wv_t  = (_Float16*)(ws + 4*MB);
  _Float16* Wp_t  = (_Float16*)(ws + 6*MB);
  _Float16* Wf1_t = (_Float16*)(ws + 8*MB);    // [4096][1024]
  _Float16* Wf2_t = (_Float16*)(ws + 16*MB);   // [1024][4096]
  _Float16* xn    = (_Float16*)(ws + 24*MB);   // [8192][1024]; reused as attn_out
  _Float16* attn_o= (_Float16*)(ws + 24*MB);
  _Float16* qbuf  = (_Float16*)(ws + 40*MB);   // [b][h][t][d]
  _Float16* kbuf  = (_Float16*)(ws + 56*MB);
  _Float16* vtbuf = (_Float16*)(ws + 72*MB);   // [b][h][d][t]
  _Float16* hbuf  = (_Float16*)(ws + 40*MB);   // [8192][4096]; overlays q/k/vt (dead by FF1)
  float*    x2    = (float*)   (ws + 104*MB);  // [8192][1024] f32
  _Float16* xn2   = (_Float16*)(ws + 136*MB);  // [8192][1024]

  dim3 tb(32, 8);
  transpose_f32_f16<<<dim3(2, 32, 16), tb, 0, stream>>>(wq, Wq_t, 1024, 64);
  transpose_f32_f16<<<dim3(2, 32, 16), tb, 0, stream>>>(wk, Wk_t, 1024, 64);
  transpose_f32_f16<<<dim3(2, 32, 16), tb, 0, stream>>>(wv, Wv_t, 1024, 64);
  transpose_f32_f16<<<dim3(32, 32, 1), tb, 0, stream>>>(w_proj, Wp_t, 1024, 1024);
  transpose_f32_f16<<<dim3(128, 32, 1), tb, 0, stream>>>(w_ff1, Wf1_t, 1024, 4096);
  transpose_f32_f16<<<dim3(32, 128, 1), tb, 0, stream>>>(w_ff2, Wf2_t, 4096, 1024);

  ln_row<<<Mr, 256, 0, stream>>>(x, ln1s, ln1b, xn);

  gemm_bt<EPI_QK><<<dim3(8, 64), 256, 0, stream>>>(xn, Wq_t, qbuf, nullptr, nullptr, Mr, Cn, Cn);
  gemm_bt<EPI_QK><<<dim3(8, 64), 256, 0, stream>>>(xn, Wk_t, kbuf, nullptr, nullptr, Mr, Cn, Cn);
  gemm_bt<EPI_V ><<<dim3(8, 64), 256, 0, stream>>>(xn, Wv_t, vtbuf, nullptr, nullptr, Mr, Cn, Cn);

  attn_kernel<<<dim3(Tn/128, Hn, Bn), 256, 0, stream>>>(qbuf, kbuf, vtbuf, attn_o);

  gemm_bt<EPI_PROJ><<<dim3(8, 64), 256, 0, stream>>>(attn_o, Wp_t, x2, b_proj, x, Mr, Cn, Cn);

  ln_row<<<Mr, 256, 0, stream>>>(x2, ln2s, ln2b, xn2);

  gemm_bt<EPI_FF1><<<dim3(32, 64), 256, 0, stream>>>(xn2, Wf1_t, hbuf, b_ff1, nullptr, Mr, 4*Cn, Cn);
  gemm_bt<EPI_FF2><<<dim3(8, 64), 256, 0, stream>>>(hbuf, Wf2_t, outp, b_ff2, x2, Mr, Cn, 4*Cn);
}

// Round 3
// 620.591 us; speedup vs baseline: 1.1599x; 1.0693x over previous
//
#include <hip/hip_runtime.h>

// ---------------- constants ----------------
#define Bn 4
#define Tn 2048
#define Cn 1024
#define Hn 16
#define Dn 64
#define Mr (Bn*Tn)          // 8192 rows

typedef _Float16 half8 __attribute__((ext_vector_type(8)));
typedef _Float16 half4v __attribute__((ext_vector_type(4)));
typedef float f32x4 __attribute__((ext_vector_type(4)));
typedef unsigned u32x4 __attribute__((ext_vector_type(4)));

__device__ __forceinline__ void g2l16(const void* g, void* l) {
  __builtin_amdgcn_global_load_lds((__attribute__((address_space(1))) void*)g,
                                   (__attribute__((address_space(3))) void*)l, 16, 0, 0);
}

// ---------------- transpose f32 -> f16 (B^T weight prep) ----------------
__global__ __launch_bounds__(256) void transpose_f32_f16(const float* __restrict__ in,
                                                         _Float16* __restrict__ out,
                                                         int R, int C) {
  __shared__ float tile[32][33];
  const size_t zoff = (size_t)blockIdx.z * R * C;
  in += zoff; out += zoff;
  const int c0 = blockIdx.x * 32, r0 = blockIdx.y * 32;
  const int tx = threadIdx.x, ty = threadIdx.y;
#pragma unroll
  for (int i = 0; i < 4; ++i)
    tile[ty + i*8][tx] = in[(size_t)(r0 + ty + i*8) * C + c0 + tx];
  __syncthreads();
#pragma unroll
  for (int i = 0; i < 4; ++i)
    out[(size_t)(c0 + ty + i*8) * R + r0 + tx] = (_Float16)tile[tx][ty + i*8];
}

// ---------------- LayerNorm row kernel: f32 in -> f16 out ----------------
__global__ __launch_bounds__(256) void ln_row(const float* __restrict__ x,
                                              const float* __restrict__ g,
                                              const float* __restrict__ bta,
                                              _Float16* __restrict__ out) {
  const int row = blockIdx.x;
  const float4 v = ((const float4*)(x + (size_t)row * Cn))[threadIdx.x];
  float s  = v.x + v.y + v.z + v.w;
  float ss = v.x*v.x + v.y*v.y + v.z*v.z + v.w*v.w;
#pragma unroll
  for (int m = 1; m < 64; m <<= 1) { s += __shfl_xor(s, m); ss += __shfl_xor(ss, m); }
  __shared__ float red[8];
  const int wave = threadIdx.x >> 6, lane = threadIdx.x & 63;
  if (lane == 0) { red[wave] = s; red[4 + wave] = ss; }
  __syncthreads();
  s  = red[0] + red[1] + red[2] + red[3];
  ss = red[4] + red[5] + red[6] + red[7];
  const float mean = s * (1.0f/Cn);
  const float var  = ss * (1.0f/Cn) - mean*mean;
  const float rstd = rsqrtf(var + 1e-6f);
  const int c = threadIdx.x * 4;
  const float4 gg = ((const float4*)g)[threadIdx.x];
  const float4 bb = ((const float4*)bta)[threadIdx.x];
  half4v o;
  o[0] = (_Float16)((v.x - mean) * rstd * gg.x + bb.x);
  o[1] = (_Float16)((v.y - mean) * rstd * gg.y + bb.y);
  o[2] = (_Float16)((v.z - mean) * rstd * gg.z + bb.z);
  o[3] = (_Float16)((v.w - mean) * rstd * gg.w + bb.w);
  *((half4v*)(out + (size_t)row * Cn + c)) = o;
}

// ---------------- GEMM: C[M,N] = A[M,K] * Bt[N,K]^T, m97 structure ----------------
enum { EPI_QK = 0, EPI_V = 1, EPI_PROJ = 2, EPI_FF1 = 3, EPI_FF2 = 4 };

template<int EPI>
__global__ __launch_bounds__(256) void gemm_bt(const _Float16* __restrict__ A,
                                               const _Float16* __restrict__ Bt,
                                               void* __restrict__ outp,
                                               const float* __restrict__ bias,
                                               const float* __restrict__ resid,
                                               int M, int N, int K) {
  __shared__ __align__(16) _Float16 As[128*64];
  __shared__ __align__(16) _Float16 Bs[128*64];
  const int tid = threadIdx.x, wave = tid >> 6, lane = tid & 63;
  const int lr = lane & 15, lg = lane >> 4;
  const int brow = blockIdx.y * 128, bcol = blockIdx.x * 128;
  const int wrow = (wave >> 1) * 64, wcol = (wave & 1) * 64;
  f32x4 acc[4][4] = {};

  for (int kt = 0; kt < K; kt += 64) {
#pragma unroll
    for (int i = 0; i < 4; ++i) {
      const int chunk = i*4 + wave;          // 16 chunks of 1KB per 128x64 tile
      const int e = chunk*512 + lane*8;      // element index
      const int rr = e >> 6, cc = e & 63;
      g2l16(A  + (size_t)(brow + rr)*K + kt + cc, As + chunk*512);
      g2l16(Bt + (size_t)(bcol + rr)*K + kt + cc, Bs + chunk*512);
    }
    __syncthreads();
#pragma unroll
    for (int kk = 0; kk < 64; kk += 32) {
      half8 af[4], bfr[4];
#pragma unroll
      for (int i = 0; i < 4; ++i) af[i]  = *(const half8*)(As + (wrow + i*16 + lr)*64 + kk + lg*8);
#pragma unroll
      for (int j = 0; j < 4; ++j) bfr[j] = *(const half8*)(Bs + (wcol + j*16 + lr)*64 + kk + lg*8);
#pragma unroll
      for (int i = 0; i < 4; ++i)
#pragma unroll
        for (int j = 0; j < 4; ++j)
          acc[i][j] = __builtin_amdgcn_mfma_f32_16x16x32_f16(af[i], bfr[j], acc[i][j], 0, 0, 0);
    }
    __syncthreads();
  }

  // C/D frag: col = lane&15, row = (lane>>4)*4 + r
  const int r0 = brow + wrow + lg*4;
  const int c0 = bcol + wcol + lr;
#pragma unroll
  for (int i = 0; i < 4; ++i) {
#pragma unroll
    for (int j = 0; j < 4; ++j) {
      const int col = c0 + j*16;
#pragma unroll
      for (int r = 0; r < 4; ++r) {
        const int row = r0 + i*16 + r;
        const float v = acc[i][j][r];
        if constexpr (EPI == EPI_QK) {
          ((_Float16*)outp)[(((size_t)(row >> 11) * Hn + (col >> 6)) * Tn + (row & 2047)) * Dn + (col & 63)] = (_Float16)v;
        } else if constexpr (EPI == EPI_V) {
          ((_Float16*)outp)[(((size_t)(row >> 11) * Hn + (col >> 6)) * Dn + (col & 63)) * Tn + (row & 2047)] = (_Float16)v;
        } else if constexpr (EPI == EPI_PROJ || EPI == EPI_FF2) {
          ((float*)outp)[(size_t)row * N + col] = v + bias[col] + resid[(size_t)row * N + col];
        } else if constexpr (EPI == EPI_FF1) {
          const float t = v + bias[col];
          ((_Float16*)outp)[(size_t)row * N + col] = (_Float16)(t > 0.f ? t : 0.f);
        }
      }
    }
  }
}

// ---------------- Flash attention (causal), paired q-tiles, KVBLK=64 ----------------
// Block handles q-tiles qtA = i*128 (light) and qtB = (15-i)*128 (heavy):
// uniform per-block work (34 tile-iters) and one shared K/V staging pass.
// Swapped-QK^T; in-register softmax; P redistributed via shuffles (no P LDS).
// K/V double-buffered in swizzled LDS (chunk ^= row&7 on 16B chunks).
// q,k: [b][h][t][d] f16; vt: [b][h][d][t] f16; out: [b*T][C] f16
__global__ __launch_bounds__(256) void attn_kernel(const _Float16* __restrict__ q,
                                                   const _Float16* __restrict__ k,
                                                   const _Float16* __restrict__ vt,
                                                   _Float16* __restrict__ out) {
  const int pi = blockIdx.x;                 // 0..7
  const int qtA = pi * 128;
  const int qtB = (15 - pi) * 128;
  const int h = blockIdx.y, b = blockIdx.z;
  const int tid = threadIdx.x, wave = tid >> 6, lane = tid & 63;
  const int lr = lane & 15, lg = lane >> 4;
  const size_t bh = (size_t)b * Hn + h;
  const _Float16* qg = q  + bh * (Tn * Dn);
  const _Float16* kg = k  + bh * (Tn * Dn);
  const _Float16* vg = vt + bh * (Dn * Tn);

  __shared__ __align__(16) _Float16 Ks[2][64*64];
  __shared__ __align__(16) _Float16 Vs[2][64*64];

  // Q fragments (B-operand), pre-scaled by C^-0.5 = 2^-5 (exact in f16)
  const _Float16 qsc = (_Float16)0.03125f;
  half8 qfA[2][2], qfB[2][2];
#pragma unroll
  for (int qi = 0; qi < 2; ++qi)
#pragma unroll
    for (int dh = 0; dh < 2; ++dh) {
      half8 a = *(const half8*)(qg + (size_t)(qtA + wave*32 + qi*16 + lr)*Dn + dh*32 + lg*8);
      half8 c = *(const half8*)(qg + (size_t)(qtB + wave*32 + qi*16 + lr)*Dn + dh*32 + lg*8);
#pragma unroll
      for (int j = 0; j < 8; ++j) { a[j] *= qsc; c[j] *= qsc; }
      qfA[qi][dh] = a; qfB[qi][dh] = c;
    }

  f32x4 oaccA[2][4] = {}, oaccB[2][4] = {};
  float mrowA[2] = {-__builtin_inff(), -__builtin_inff()};
  float mrowB[2] = {-__builtin_inff(), -__builtin_inff()};
  float lsumA[2] = {0.f, 0.f}, lsumB[2] = {0.f, 0.f};

  const int ntB = (qtB >> 6) + 2;            // staging covers B's full range

  auto STAGE = [&](int bufi, int t) {
    const int kvt = t * 64;
#pragma unroll
    for (int r = 0; r < 2; ++r) {
      const int g0 = r*256 + wave*64;          // wave-uniform chunk base
      const int g  = g0 + lane;                // this lane's chunk id (0..511)
      const int rr = g >> 3;                   // tile row
      const int cs = (g & 7) ^ (rr & 7);       // inverse-swizzled source chunk
      g2l16(kg + (size_t)(kvt + rr)*Dn + cs*8, &Ks[bufi][g0*8]);
      g2l16(vg + (size_t)rr*Tn + kvt + cs*8,   &Vs[bufi][g0*8]);
    }
  };

  auto COMPUTE = [&](const half8 (&qf)[2][2], f32x4 (&oacc)[2][4],
                     float* mrow, float* lsum, int qb,
                     const _Float16* KS, const _Float16* VS, int kvt) {
    // K fragments (A-operand): row = 16f+lr, swizzled chunk = (4dh+lg)^(lr&7)
    half8 kb[4][2];
#pragma unroll
    for (int f = 0; f < 4; ++f)
#pragma unroll
      for (int dh = 0; dh < 2; ++dh)
        kb[f][dh] = *(const half8*)(KS + (16*f + lr)*64 + (((4*dh + lg) ^ (lr & 7)) * 8));

#pragma unroll
    for (int qi = 0; qi < 2; ++qi) {
      // S^T frags: lane holds S[q=qrow][kv=kvt+16f+4lg+r]
      f32x4 sv[4];
#pragma unroll
      for (int f = 0; f < 4; ++f) {
        f32x4 tacc = {0.f, 0.f, 0.f, 0.f};
        tacc = __builtin_amdgcn_mfma_f32_16x16x32_f16(kb[f][0], qf[qi][0], tacc, 0, 0, 0);
        tacc = __builtin_amdgcn_mfma_f32_16x16x32_f16(kb[f][1], qf[qi][1], tacc, 0, 0, 0);
        sv[f] = tacc;
      }
      const int qrow = qb + wave*32 + qi*16 + lr;
      // mask (Q pre-scaled; masked stay -inf, matching reference)
#pragma unroll
      for (int f = 0; f < 4; ++f)
#pragma unroll
        for (int r = 0; r < 4; ++r) {
          const int kvv = kvt + 16*f + 4*lg + r;
          sv[f][r] = (kvv > qrow) ? -__builtin_inff() : sv[f][r];
        }
      // row max: 15 local fmax + 2 shfl
      float tm = sv[0][0];
#pragma unroll
      for (int f = 0; f < 4; ++f)
#pragma unroll
        for (int r = 0; r < 4; ++r) tm = fmaxf(tm, sv[f][r]);
      tm = fmaxf(tm, __shfl_xor(tm, 16));
      tm = fmaxf(tm, __shfl_xor(tm, 32));
      const float mn = fmaxf(mrow[qi], tm);
      const float alpha = __expf(mrow[qi] - mn);
      mrow[qi] = mn;
      float ps = 0.f;
#pragma unroll
      for (int f = 0; f < 4; ++f)
#pragma unroll
        for (int r = 0; r < 4; ++r) {
          const float e = __expf(sv[f][r] - mn);
          ps += e;
          sv[f][r] = e;
        }
      ps += __shfl_xor(ps, 16);
      ps += __shfl_xor(ps, 32);
      lsum[qi] = lsum[qi] * alpha + ps;
      // pack P to f16 pairs
      unsigned ph[4][2];
#pragma unroll
      for (int f = 0; f < 4; ++f)
#pragma unroll
        for (int m = 0; m < 2; ++m) {
          const unsigned lo = (unsigned)__builtin_bit_cast(unsigned short, (_Float16)sv[f][2*m]);
          const unsigned hi = (unsigned)__builtin_bit_cast(unsigned short, (_Float16)sv[f][2*m + 1]);
          ph[f][m] = lo | (hi << 16);
        }
      // rescale O rows (oacc row q_local = 4lg+r; alpha lives at lane q_local)
      float ab[4];
#pragma unroll
      for (int r = 0; r < 4; ++r) ab[r] = __shfl(alpha, 4*lg + r);
#pragma unroll
      for (int df = 0; df < 4; ++df)
#pragma unroll
        for (int r = 0; r < 4; ++r) oacc[qi][df][r] *= ab[r];
      // redistribute P -> PV A-frags
      const int s0 = lr + 16*(2*(lg & 1));
      const int s1 = s0 + 16;
      half8 pa[2];
#pragma unroll
      for (int kh = 0; kh < 2; ++kh) {
        u32x4 w = {0u, 0u, 0u, 0u};
#pragma unroll
        for (int fi = 0; fi < 2; ++fi) {
          const unsigned a0 = __shfl(ph[2*kh + fi][0], s0);
          const unsigned a1 = __shfl(ph[2*kh + fi][1], s0);
          const unsigned a2 = __shfl(ph[2*kh + fi][0], s1);
          const unsigned a3 = __shfl(ph[2*kh + fi][1], s1);
          const bool sel = ((lg >> 1) == fi);
          w[0] = sel ? a0 : w[0];
          w[1] = sel ? a1 : w[1];
          w[2] = sel ? a2 : w[2];
          w[3] = sel ? a3 : w[3];
        }
        pa[kh] = __builtin_bit_cast(half8, w);
      }
      // PV: O[q][d] += P * V ; B-operand from Vt tile, swizzled reads
#pragma unroll
      for (int df = 0; df < 4; ++df) {
        half8 vb0 = *(const half8*)(VS + (16*df + lr)*64 + (((0 + lg) ^ (lr & 7)) * 8));
        half8 vb1 = *(const half8*)(VS + (16*df + lr)*64 + (((4 + lg) ^ (lr & 7)) * 8));
        oacc[qi][df] = __builtin_amdgcn_mfma_f32_16x16x32_f16(pa[0], vb0, oacc[qi][df], 0, 0, 0);
        oacc[qi][df] = __builtin_amdgcn_mfma_f32_16x16x32_f16(pa[1], vb1, oacc[qi][df], 0, 0, 0);
      }
    }
  };

  STAGE(0, 0);
  __syncthreads();

  for (int t = 0; t < ntB; ++t) {
    const int kvt = t * 64;
    if (t + 1 < ntB) STAGE((t + 1) & 1, t + 1);   // prefetch next tile
    const _Float16* KS = Ks[t & 1];
    const _Float16* VS = Vs[t & 1];
    if (kvt <= qtA + wave*32 + 31) COMPUTE(qfA, oaccA, mrowA, lsumA, qtA, KS, VS, kvt);
    if (kvt <= qtB + wave*32 + 31) COMPUTE(qfB, oaccB, mrowB, lsumB, qtB, KS, VS, kvt);
    __syncthreads();
  }

  // epilogue: out[b*T + row][h*64 + d]
  auto EPI = [&](const f32x4 (&oacc)[2][4], const float* lsum, int qb) {
#pragma unroll
    for (int qi = 0; qi < 2; ++qi) {
      const float linv = 1.0f / lsum[qi];
      float lb[4];
#pragma unroll
      for (int r = 0; r < 4; ++r) lb[r] = __shfl(linv, 4*lg + r);
#pragma unroll
      for (int df = 0; df < 4; ++df)
#pragma unroll
        for (int r = 0; r < 4; ++r) {
          const int row = qb + wave*32 + qi*16 + 4*lg + r;
          const int col = h*Dn + df*16 + lr;
          out[((size_t)b*Tn + row)*Cn + col] = (_Float16)(oacc[qi][df][r] * lb[r]);
        }
    }
  };
  EPI(oaccA, lsumA, qtA);
  EPI(oaccB, lsumB, qtB);
}

// ---------------- host launch ----------------
extern "C" void kernel_launch(void* const* d_in, const int* in_sizes, int n_in,
                              void* d_out, int out_size, void* d_ws, size_t ws_size,
                              hipStream_t stream) {
  const float* x      = (const float*)d_in[0];
  const float* wq     = (const float*)d_in[1];
  const float* wk     = (const float*)d_in[2];
  const float* wv     = (const float*)d_in[3];
  const float* w_proj = (const float*)d_in[4];
  const float* b_proj = (const float*)d_in[5];
  const float* w_ff1  = (const float*)d_in[6];
  const float* b_ff1  = (const float*)d_in[7];
  const float* w_ff2  = (const float*)d_in[8];
  const float* b_ff2  = (const float*)d_in[9];
  const float* ln1s   = (const float*)d_in[10];
  const float* ln1b   = (const float*)d_in[11];
  const float* ln2s   = (const float*)d_in[12];
  const float* ln2b   = (const float*)d_in[13];
  float* outp = (float*)d_out;

  char* ws = (char*)d_ws;
  constexpr size_t MB = (size_t)1 << 20;
  _Float16* Wq_t  = (_Float16*)(ws + 0*MB);    // [1024][1024]
  _Float16* Wk_t  = (_Float16*)(ws + 2*MB);
  _Float16* Wv_t  = (_Float16*)(ws + 4*MB);
  _Float16* Wp_t  = (_Float16*)(ws + 6*MB);
  _Float16* Wf1_t = (_Float16*)(ws + 8*MB);    // [4096][1024]
  _Float16* Wf2_t = (_Float16*)(ws + 16*MB);   // [1024][4096]
  _Float16* xn    = (_Float16*)(ws + 24*MB);   // [8192][1024]; reused as attn_out
  _Float16* attn_o= (_Float16*)(ws + 24*MB);
  _Float16* qbuf  = (_Float16*)(ws + 40*MB);   // [b][h][t][d]
  _Float16* kbuf  = (_Float16*)(ws + 56*MB);
  _Float16* vtbuf = (_Float16*)(ws + 72*MB);   // [b][h][d][t]
  _Float16* hbuf  = (_Float16*)(ws + 40*MB);   // [8192][4096]; overlays q/k/vt (dead by FF1)
  float*    x2    = (float*)   (ws + 104*MB);  // [8192][1024] f32
  _Float16* xn2   = (_Float16*)(ws + 136*MB);  // [8192][1024]

  dim3 tb(32, 8);
  transpose_f32_f16<<<dim3(2, 32, 16), tb, 0, stream>>>(wq, Wq_t, 1024, 64);
  transpose_f32_f16<<<dim3(2, 32, 16), tb, 0, stream>>>(wk, Wk_t, 1024, 64);
  transpose_f32_f16<<<dim3(2, 32, 16), tb, 0, stream>>>(wv, Wv_t, 1024, 64);
  transpose_f32_f16<<<dim3(32, 32, 1), tb, 0, stream>>>(w_proj, Wp_t, 1024, 1024);
  transpose_f32_f16<<<dim3(128, 32, 1), tb, 0, stream>>>(w_ff1, Wf1_t, 1024, 4096);
  transpose_f32_f16<<<dim3(32, 128, 1), tb, 0, stream>>>(w_ff2, Wf2_t, 4096, 1024);

  ln_row<<<Mr, 256, 0, stream>>>(x, ln1s, ln1b, xn);

  gemm_bt<EPI_QK><<<dim3(8, 64), 256, 0, stream>>>(xn, Wq_t, qbuf, nullptr, nullptr, Mr, Cn, Cn);
  gemm_bt<EPI_QK><<<dim3(8, 64), 256, 0, stream>>>(xn, Wk_t, kbuf, nullptr, nullptr, Mr, Cn, Cn);
  gemm_bt<EPI_V ><<<dim3(8, 64), 256, 0, stream>>>(xn, Wv_t, vtbuf, nullptr, nullptr, Mr, Cn, Cn);

  attn_kernel<<<dim3(8, Hn, Bn), 256, 0, stream>>>(qbuf, kbuf, vtbuf, attn_o);

  gemm_bt<EPI_PROJ><<<dim3(8, 64), 256, 0, stream>>>(attn_o, Wp_t, x2, b_proj, x, Mr, Cn, Cn);

  ln_row<<<Mr, 256, 0, stream>>>(x2, ln2s, ln2b, xn2);

  gemm_bt<EPI_FF1><<<dim3(32, 64), 256, 0, stream>>>(xn2, Wf1_t, hbuf, b_ff1, nullptr, Mr, 4*Cn, Cn);
  gemm_bt<EPI_FF2><<<dim3(8, 64), 256, 0, stream>>>(hbuf, Wf2_t, outp, b_ff2, x2, Mr, Cn, 4*Cn);
}

// Round 4
// 614.632 us; speedup vs baseline: 1.1712x; 1.0097x over previous
//
#include <hip/hip_runtime.h>

// ---------------- constants ----------------
#define Bn 4
#define Tn 2048
#define Cn 1024
#define Hn 16
#define Dn 64
#define Mr (Bn*Tn)          // 8192 rows

typedef _Float16 half8 __attribute__((ext_vector_type(8)));
typedef _Float16 half4v __attribute__((ext_vector_type(4)));
typedef float f32x4 __attribute__((ext_vector_type(4)));
typedef unsigned u32x4 __attribute__((ext_vector_type(4)));

__device__ __forceinline__ void g2l16(const void* g, void* l) {
  __builtin_amdgcn_global_load_lds((__attribute__((address_space(1))) void*)g,
                                   (__attribute__((address_space(3))) void*)l, 16, 0, 0);
}

// ---------------- transpose f32 -> f16 (B^T weight prep) ----------------
__global__ __launch_bounds__(256) void transpose_f32_f16(const float* __restrict__ in,
                                                         _Float16* __restrict__ out,
                                                         int R, int C) {
  __shared__ float tile[32][33];
  const size_t zoff = (size_t)blockIdx.z * R * C;
  in += zoff; out += zoff;
  const int c0 = blockIdx.x * 32, r0 = blockIdx.y * 32;
  const int tx = threadIdx.x, ty = threadIdx.y;
#pragma unroll
  for (int i = 0; i < 4; ++i)
    tile[ty + i*8][tx] = in[(size_t)(r0 + ty + i*8) * C + c0 + tx];
  __syncthreads();
#pragma unroll
  for (int i = 0; i < 4; ++i)
    out[(size_t)(c0 + ty + i*8) * R + r0 + tx] = (_Float16)tile[tx][ty + i*8];
}

// ---------------- LayerNorm row kernel: f32 in -> f16 out ----------------
__global__ __launch_bounds__(256) void ln_row(const float* __restrict__ x,
                                              const float* __restrict__ g,
                                              const float* __restrict__ bta,
                                              _Float16* __restrict__ out) {
  const int row = blockIdx.x;
  const float4 v = ((const float4*)(x + (size_t)row * Cn))[threadIdx.x];
  float s  = v.x + v.y + v.z + v.w;
  float ss = v.x*v.x + v.y*v.y + v.z*v.z + v.w*v.w;
#pragma unroll
  for (int m = 1; m < 64; m <<= 1) { s += __shfl_xor(s, m); ss += __shfl_xor(ss, m); }
  __shared__ float red[8];
  const int wave = threadIdx.x >> 6, lane = threadIdx.x & 63;
  if (lane == 0) { red[wave] = s; red[4 + wave] = ss; }
  __syncthreads();
  s  = red[0] + red[1] + red[2] + red[3];
  ss = red[4] + red[5] + red[6] + red[7];
  const float mean = s * (1.0f/Cn);
  const float var  = ss * (1.0f/Cn) - mean*mean;
  const float rstd = rsqrtf(var + 1e-6f);
  const int c = threadIdx.x * 4;
  const float4 gg = ((const float4*)g)[threadIdx.x];
  const float4 bb = ((const float4*)bta)[threadIdx.x];
  half4v o;
  o[0] = (_Float16)((v.x - mean) * rstd * gg.x + bb.x);
  o[1] = (_Float16)((v.y - mean) * rstd * gg.y + bb.y);
  o[2] = (_Float16)((v.z - mean) * rstd * gg.z + bb.z);
  o[3] = (_Float16)((v.w - mean) * rstd * gg.w + bb.w);
  *((half4v*)(out + (size_t)row * Cn + c)) = o;
}

// ---------------- GEMM v2: BM=256 tile, 512 thr / 8 waves, counted vmcnt ----------------
// C[M,N] = A[M,K] * Bt[N,K]^T. Double-buffered LDS (K-tile granular), raw s_barrier,
// s_waitcnt vmcnt(VMC) never 0 in main loop (T4), setprio around MFMA (T5),
// chunk-XOR swizzle both-sides (T2-style, validated in attn).
enum { EPI_QKV = 0, EPI_PROJ = 2, EPI_FF1 = 3, EPI_FF2 = 4 };

template<int BN, int EPI>
__global__ __launch_bounds__(512, 1) void gemm8(const _Float16* __restrict__ A,
                                                const _Float16* __restrict__ Bt,
                                                void* __restrict__ outp,
                                                void* __restrict__ out2,   // EPI_QKV: k
                                                void* __restrict__ out3,   // EPI_QKV: vt
                                                const float* __restrict__ bias,
                                                const float* __restrict__ resid,
                                                int M, int N, int K) {
  constexpr int MI  = (BN == 256) ? 8 : 4;       // M-frags per wave
  constexpr int VMC = 4 + BN/64;                 // loads per wave per K-tile
  __shared__ __align__(16) _Float16 As[2][256*64];
  __shared__ __align__(16) _Float16 Bs[2][BN*64];

  const int tid = threadIdx.x, wave = tid >> 6, lane = tid & 63;
  const int lr = lane & 15, lg = lane >> 4;
  const int brow = blockIdx.y * 256, bcol = blockIdx.x * BN;
  const int WROW = (BN == 256) ? (wave >> 2) * 128 : (wave >> 1) * 64;
  const int WCOL = ((BN == 256) ? (wave & 3) : (wave & 1)) * 64;

  f32x4 acc[MI][4] = {};

  auto STG = [&](int buf, int kt) {
    const int kc = kt * 64;
#pragma unroll
    for (int i = 0; i < 4; ++i) {                 // A: 256x64 = 2048 chunks
      const int g0 = i*512 + wave*64;
      const int g = g0 + lane;
      const int rr = g >> 3, cs = (g & 7) ^ (rr & 7);
      g2l16(A + (size_t)(brow + rr)*K + kc + cs*8, &As[buf][g0*8]);
    }
#pragma unroll
    for (int i = 0; i < BN/64; ++i) {             // B: BNx64 chunks
      const int g0 = i*512 + wave*64;
      const int g = g0 + lane;
      const int rr = g >> 3, cs = (g & 7) ^ (rr & 7);
      g2l16(Bt + (size_t)(bcol + rr)*K + kc + cs*8, &Bs[buf][g0*8]);
    }
  };

  const int nt = K >> 6;
  STG(0, 0);
  for (int kt = 0; kt < nt; ++kt) {
    const int buf = kt & 1;
    if (kt + 1 < nt) {
      STG(buf ^ 1, kt + 1);
      asm volatile("s_waitcnt vmcnt(%0)" :: "i"(VMC) : "memory");
    } else {
      asm volatile("s_waitcnt vmcnt(0)" ::: "memory");
    }
    __builtin_amdgcn_s_barrier();
    __builtin_amdgcn_sched_barrier(0);
    const _Float16* AS = As[buf];
    const _Float16* BS = Bs[buf];
#pragma unroll
    for (int kh = 0; kh < 2; ++kh) {
      half8 af[MI], bfr[4];
#pragma unroll
      for (int i = 0; i < MI; ++i)
        af[i] = *(const half8*)(AS + (WROW + i*16 + lr)*64 + (((4*kh + lg) ^ (lr & 7)) * 8));
#pragma unroll
      for (int j = 0; j < 4; ++j)
        bfr[j] = *(const half8*)(BS + (WCOL + j*16 + lr)*64 + (((4*kh + lg) ^ (lr & 7)) * 8));
      __builtin_amdgcn_s_setprio(1);
#pragma unroll
      for (int i = 0; i < MI; ++i)
#pragma unroll
        for (int j = 0; j < 4; ++j)
          acc[i][j] = __builtin_amdgcn_mfma_f32_16x16x32_f16(af[i], bfr[j], acc[i][j], 0, 0, 0);
      __builtin_amdgcn_s_setprio(0);
    }
    __builtin_amdgcn_sched_barrier(0);
    __builtin_amdgcn_s_barrier();
  }

  // C/D frag: col = lane&15, row = lg*4 + r
#pragma unroll
  for (int i = 0; i < MI; ++i) {
#pragma unroll
    for (int j = 0; j < 4; ++j) {
      const int col = bcol + WCOL + j*16 + lr;
#pragma unroll
      for (int r = 0; r < 4; ++r) {
        const int row = brow + WROW + i*16 + lg*4 + r;
        const float v = acc[i][j][r];
        if constexpr (EPI == EPI_QKV) {
          const int sel = col >> 10;            // 0:q 1:k 2:v
          const int cw = col & 1023;
          const int hh = cw >> 6, dd = cw & 63;
          const size_t bhh = (size_t)(row >> 11) * Hn + hh;
          const int t = row & 2047;
          if (sel == 0)      ((_Float16*)outp)[(bhh*Tn + t)*Dn + dd] = (_Float16)v;
          else if (sel == 1) ((_Float16*)out2)[(bhh*Tn + t)*Dn + dd] = (_Float16)v;
          else               ((_Float16*)out3)[(bhh*Dn + dd)*Tn + t] = (_Float16)v;
        } else if constexpr (EPI == EPI_PROJ || EPI == EPI_FF2) {
          ((float*)outp)[(size_t)row * N + col] = v + bias[col] + resid[(size_t)row * N + col];
        } else if constexpr (EPI == EPI_FF1) {
          const float t = v + bias[col];
          ((_Float16*)outp)[(size_t)row * N + col] = (_Float16)(t > 0.f ? t : 0.f);
        }
      }
    }
  }
}

// ---------------- Flash attention (causal), paired q-tiles, KVBLK=64 ----------------
// Block handles q-tiles qtA = i*128 (light) and qtB = (15-i)*128 (heavy):
// uniform per-block work and one shared K/V staging pass.
// Swapped-QK^T; in-register softmax; P redistributed via shuffles (no P LDS).
__global__ __launch_bounds__(256) void attn_kernel(const _Float16* __restrict__ q,
                                                   const _Float16* __restrict__ k,
                                                   const _Float16* __restrict__ vt,
                                                   _Float16* __restrict__ out) {
  const int pi = blockIdx.x;                 // 0..7
  const int qtA = pi * 128;
  const int qtB = (15 - pi) * 128;
  const int h = blockIdx.y, b = blockIdx.z;
  const int tid = threadIdx.x, wave = tid >> 6, lane = tid & 63;
  const int lr = lane & 15, lg = lane >> 4;
  const size_t bh = (size_t)b * Hn + h;
  const _Float16* qg = q  + bh * (Tn * Dn);
  const _Float16* kg = k  + bh * (Tn * Dn);
  const _Float16* vg = vt + bh * (Dn * Tn);

  __shared__ __align__(16) _Float16 Ks[2][64*64];
  __shared__ __align__(16) _Float16 Vs[2][64*64];

  const _Float16 qsc = (_Float16)0.03125f;   // C^-0.5 = 2^-5, exact in f16
  half8 qfA[2][2], qfB[2][2];
#pragma unroll
  for (int qi = 0; qi < 2; ++qi)
#pragma unroll
    for (int dh = 0; dh < 2; ++dh) {
      half8 a = *(const half8*)(qg + (size_t)(qtA + wave*32 + qi*16 + lr)*Dn + dh*32 + lg*8);
      half8 c = *(const half8*)(qg + (size_t)(qtB + wave*32 + qi*16 + lr)*Dn + dh*32 + lg*8);
#pragma unroll
      for (int j = 0; j < 8; ++j) { a[j] *= qsc; c[j] *= qsc; }
      qfA[qi][dh] = a; qfB[qi][dh] = c;
    }

  f32x4 oaccA[2][4] = {}, oaccB[2][4] = {};
  float mrowA[2] = {-__builtin_inff(), -__builtin_inff()};
  float mrowB[2] = {-__builtin_inff(), -__builtin_inff()};
  float lsumA[2] = {0.f, 0.f}, lsumB[2] = {0.f, 0.f};

  const int ntB = (qtB >> 6) + 2;

  auto STAGE = [&](int bufi, int t) {
    const int kvt = t * 64;
#pragma unroll
    for (int r = 0; r < 2; ++r) {
      const int g0 = r*256 + wave*64;
      const int g  = g0 + lane;
      const int rr = g >> 3;
      const int cs = (g & 7) ^ (rr & 7);
      g2l16(kg + (size_t)(kvt + rr)*Dn + cs*8, &Ks[bufi][g0*8]);
      g2l16(vg + (size_t)rr*Tn + kvt + cs*8,   &Vs[bufi][g0*8]);
    }
  };

  auto COMPUTE = [&](const half8 (&qf)[2][2], f32x4 (&oacc)[2][4],
                     float* mrow, float* lsum, int qb,
                     const _Float16* KS, const _Float16* VS, int kvt) {
    half8 kb[4][2];
#pragma unroll
    for (int f = 0; f < 4; ++f)
#pragma unroll
      for (int dh = 0; dh < 2; ++dh)
        kb[f][dh] = *(const half8*)(KS + (16*f + lr)*64 + (((4*dh + lg) ^ (lr & 7)) * 8));

#pragma unroll
    for (int qi = 0; qi < 2; ++qi) {
      f32x4 sv[4];
#pragma unroll
      for (int f = 0; f < 4; ++f) {
        f32x4 tacc = {0.f, 0.f, 0.f, 0.f};
        tacc = __builtin_amdgcn_mfma_f32_16x16x32_f16(kb[f][0], qf[qi][0], tacc, 0, 0, 0);
        tacc = __builtin_amdgcn_mfma_f32_16x16x32_f16(kb[f][1], qf[qi][1], tacc, 0, 0, 0);
        sv[f] = tacc;
      }
      const int qrow = qb + wave*32 + qi*16 + lr;
#pragma unroll
      for (int f = 0; f < 4; ++f)
#pragma unroll
        for (int r = 0; r < 4; ++r) {
          const int kvv = kvt + 16*f + 4*lg + r;
          sv[f][r] = (kvv > qrow) ? -__builtin_inff() : sv[f][r];
        }
      float tm = sv[0][0];
#pragma unroll
      for (int f = 0; f < 4; ++f)
#pragma unroll
        for (int r = 0; r < 4; ++r) tm = fmaxf(tm, sv[f][r]);
      tm = fmaxf(tm, __shfl_xor(tm, 16));
      tm = fmaxf(tm, __shfl_xor(tm, 32));
      const float mn = fmaxf(mrow[qi], tm);
      const float alpha = __expf(mrow[qi] - mn);
      mrow[qi] = mn;
      float ps = 0.f;
#pragma unroll
      for (int f = 0; f < 4; ++f)
#pragma unroll
        for (int r = 0; r < 4; ++r) {
          const float e = __expf(sv[f][r] - mn);
          ps += e;
          sv[f][r] = e;
        }
      ps += __shfl_xor(ps, 16);
      ps += __shfl_xor(ps, 32);
      lsum[qi] = lsum[qi] * alpha + ps;
      unsigned ph[4][2];
#pragma unroll
      for (int f = 0; f < 4; ++f)
#pragma unroll
        for (int m = 0; m < 2; ++m) {
          const unsigned lo = (unsigned)__builtin_bit_cast(unsigned short, (_Float16)sv[f][2*m]);
          const unsigned hi = (unsigned)__builtin_bit_cast(unsigned short, (_Float16)sv[f][2*m + 1]);
          ph[f][m] = lo | (hi << 16);
        }
      float ab[4];
#pragma unroll
      for (int r = 0; r < 4; ++r) ab[r] = __shfl(alpha, 4*lg + r);
#pragma unroll
      for (int df = 0; df < 4; ++df)
#pragma unroll
        for (int r = 0; r < 4; ++r) oacc[qi][df][r] *= ab[r];
      const int s0 = lr + 16*(2*(lg & 1));
      const int s1 = s0 + 16;
      half8 pa[2];
#pragma unroll
      for (int kh = 0; kh < 2; ++kh) {
        u32x4 w = {0u, 0u, 0u, 0u};
#pragma unroll
        for (int fi = 0; fi < 2; ++fi) {
          const unsigned a0 = __shfl(ph[2*kh + fi][0], s0);
          const unsigned a1 = __shfl(ph[2*kh + fi][1], s0);
          const unsigned a2 = __shfl(ph[2*kh + fi][0], s1);
          const unsigned a3 = __shfl(ph[2*kh + fi][1], s1);
          const bool sel = ((lg >> 1) == fi);
          w[0] = sel ? a0 : w[0];
          w[1] = sel ? a1 : w[1];
          w[2] = sel ? a2 : w[2];
          w[3] = sel ? a3 : w[3];
        }
        pa[kh] = __builtin_bit_cast(half8, w);
      }
#pragma unroll
      for (int df = 0; df < 4; ++df) {
        half8 vb0 = *(const half8*)(VS + (16*df + lr)*64 + (((0 + lg) ^ (lr & 7)) * 8));
        half8 vb1 = *(const half8*)(VS + (16*df + lr)*64 + (((4 + lg) ^ (lr & 7)) * 8));
        oacc[qi][df] = __builtin_amdgcn_mfma_f32_16x16x32_f16(pa[0], vb0, oacc[qi][df], 0, 0, 0);
        oacc[qi][df] = __builtin_amdgcn_mfma_f32_16x16x32_f16(pa[1], vb1, oacc[qi][df], 0, 0, 0);
      }
    }
  };

  STAGE(0, 0);
  __syncthreads();

  for (int t = 0; t < ntB; ++t) {
    const int kvt = t * 64;
    if (t + 1 < ntB) STAGE((t + 1) & 1, t + 1);
    const _Float16* KS = Ks[t & 1];
    const _Float16* VS = Vs[t & 1];
    if (kvt <= qtA + wave*32 + 31) COMPUTE(qfA, oaccA, mrowA, lsumA, qtA, KS, VS, kvt);
    if (kvt <= qtB + wave*32 + 31) COMPUTE(qfB, oaccB, mrowB, lsumB, qtB, KS, VS, kvt);
    __syncthreads();
  }

  auto EPI = [&](const f32x4 (&oacc)[2][4], const float* lsum, int qb) {
#pragma unroll
    for (int qi = 0; qi < 2; ++qi) {
      const float linv = 1.0f / lsum[qi];
      float lb[4];
#pragma unroll
      for (int r = 0; r < 4; ++r) lb[r] = __shfl(linv, 4*lg + r);
#pragma unroll
      for (int df = 0; df < 4; ++df)
#pragma unroll
        for (int r = 0; r < 4; ++r) {
          const int row = qb + wave*32 + qi*16 + 4*lg + r;
          const int col = h*Dn + df*16 + lr;
          out[((size_t)b*Tn + row)*Cn + col] = (_Float16)(oacc[qi][df][r] * lb[r]);
        }
    }
  };
  EPI(oaccA, lsumA, qtA);
  EPI(oaccB, lsumB, qtB);
}

// ---------------- host launch ----------------
extern "C" void kernel_launch(void* const* d_in, const int* in_sizes, int n_in,
                              void* d_out, int out_size, void* d_ws, size_t ws_size,
                              hipStream_t stream) {
  const float* x      = (const float*)d_in[0];
  const float* wq     = (const float*)d_in[1];
  const float* wk     = (const float*)d_in[2];
  const float* wv     = (const float*)d_in[3];
  const float* w_proj = (const float*)d_in[4];
  const float* b_proj = (const float*)d_in[5];
  const float* w_ff1  = (const float*)d_in[6];
  const float* b_ff1  = (const float*)d_in[7];
  const float* w_ff2  = (const float*)d_in[8];
  const float* b_ff2  = (const float*)d_in[9];
  const float* ln1s   = (const float*)d_in[10];
  const float* ln1b   = (const float*)d_in[11];
  const float* ln2s   = (const float*)d_in[12];
  const float* ln2b   = (const float*)d_in[13];
  float* outp = (float*)d_out;

  char* ws = (char*)d_ws;
  constexpr size_t MB = (size_t)1 << 20;
  _Float16* Wq_t  = (_Float16*)(ws + 0*MB);    // [1024][1024]; Wq/Wk/Wv contiguous =
  _Float16* Wk_t  = (_Float16*)(ws + 2*MB);    //   fused QKV B^T [3072][1024]
  _Float16* Wv_t  = (_Float16*)(ws + 4*MB);
  _Float16* Wp_t  = (_Float16*)(ws + 6*MB);
  _Float16* Wf1_t = (_Float16*)(ws + 8*MB);    // [4096][1024]
  _Float16* Wf2_t = (_Float16*)(ws + 16*MB);   // [1024][4096]
  _Float16* xn    = (_Float16*)(ws + 24*MB);   // [8192][1024]; reused as attn_out
  _Float16* attn_o= (_Float16*)(ws + 24*MB);
  _Float16* qbuf  = (_Float16*)(ws + 40*MB);   // [b][h][t][d]
  _Float16* kbuf  = (_Float16*)(ws + 56*MB);
  _Float16* vtbuf = (_Float16*)(ws + 72*MB);   // [b][h][d][t]
  _Float16* hbuf  = (_Float16*)(ws + 40*MB);   // [8192][4096]; overlays q/k/vt (dead by FF1)
  float*    x2    = (float*)   (ws + 104*MB);  // [8192][1024] f32
  _Float16* xn2   = (_Float16*)(ws + 136*MB);  // [8192][1024]

  dim3 tb(32, 8);
  transpose_f32_f16<<<dim3(2, 32, 16), tb, 0, stream>>>(wq, Wq_t, 1024, 64);
  transpose_f32_f16<<<dim3(2, 32, 16), tb, 0, stream>>>(wk, Wk_t, 1024, 64);
  transpose_f32_f16<<<dim3(2, 32, 16), tb, 0, stream>>>(wv, Wv_t, 1024, 64);
  transpose_f32_f16<<<dim3(32, 32, 1), tb, 0, stream>>>(w_proj, Wp_t, 1024, 1024);
  transpose_f32_f16<<<dim3(128, 32, 1), tb, 0, stream>>>(w_ff1, Wf1_t, 1024, 4096);
  transpose_f32_f16<<<dim3(32, 128, 1), tb, 0, stream>>>(w_ff2, Wf2_t, 4096, 1024);

  ln_row<<<Mr, 256, 0, stream>>>(x, ln1s, ln1b, xn);

  // fused QKV: N = 3072, BN=128 -> 768 wg (3 exact rounds at 1 wg/CU)
  gemm8<128, EPI_QKV><<<dim3(24, 32), 512, 0, stream>>>(xn, Wq_t, qbuf, kbuf, vtbuf,
                                                        nullptr, nullptr, Mr, 3*Cn, Cn);

  attn_kernel<<<dim3(8, Hn, Bn), 256, 0, stream>>>(qbuf, kbuf, vtbuf, attn_o);

  // proj + residual: N=1024, BN=128 -> 256 wg (1 exact round)
  gemm8<128, EPI_PROJ><<<dim3(8, 32), 512, 0, stream>>>(attn_o, Wp_t, x2, nullptr, nullptr,
                                                        b_proj, x, Mr, Cn, Cn);

  ln_row<<<Mr, 256, 0, stream>>>(x2, ln2s, ln2b, xn2);

  // FF1: N=4096, BN=256 -> 512 wg (2 exact rounds)
  gemm8<256, EPI_FF1><<<dim3(16, 32), 512, 0, stream>>>(xn2, Wf1_t, hbuf, nullptr, nullptr,
                                                        b_ff1, nullptr, Mr, 4*Cn, Cn);
  // FF2: N=1024, K=4096, BN=128 -> 256 wg (1 exact round)
  gemm8<128, EPI_FF2><<<dim3(8, 32), 512, 0, stream>>>(hbuf, Wf2_t, outp, nullptr, nullptr,
                                                       b_ff2, x2, Mr, Cn, 4*Cn);
}

// Round 7
// 592.743 us; speedup vs baseline: 1.2144x; 1.0369x over previous
//
#include <hip/hip_runtime.h>

// ---------------- constants ----------------
#define Bn 4
#define Tn 2048
#define Cn 1024
#define Hn 16
#define Dn 64
#define Mr (Bn*Tn)          // 8192 rows

typedef _Float16 half8 __attribute__((ext_vector_type(8)));
typedef _Float16 half4v __attribute__((ext_vector_type(4)));
typedef float f32x4 __attribute__((ext_vector_type(4)));
typedef unsigned u32x4 __attribute__((ext_vector_type(4)));

__device__ __forceinline__ void g2l16(const void* g, void* l) {
  __builtin_amdgcn_global_load_lds((__attribute__((address_space(1))) void*)g,
                                   (__attribute__((address_space(3))) void*)l, 16, 0, 0);
}

#define SB  __builtin_amdgcn_sched_barrier(0)
#define BAR __builtin_amdgcn_s_barrier()
#define VMW8 asm volatile("s_waitcnt vmcnt(8)" ::: "memory")
#define VMW6 asm volatile("s_waitcnt vmcnt(6)" ::: "memory")
#define VMW4 asm volatile("s_waitcnt vmcnt(4)" ::: "memory")
#define VMW3 asm volatile("s_waitcnt vmcnt(3)" ::: "memory")
#define VMW0 asm volatile("s_waitcnt vmcnt(0)" ::: "memory")

// ---------------- transpose f32 -> f16 (B^T weight prep) ----------------
__global__ __launch_bounds__(256) void transpose_f32_f16(const float* __restrict__ in,
                                                         _Float16* __restrict__ out,
                                                         int R, int C) {
  __shared__ float tile[32][33];
  const size_t zoff = (size_t)blockIdx.z * R * C;
  in += zoff; out += zoff;
  const int c0 = blockIdx.x * 32, r0 = blockIdx.y * 32;
  const int tx = threadIdx.x, ty = threadIdx.y;
#pragma unroll
  for (int i = 0; i < 4; ++i)
    tile[ty + i*8][tx] = in[(size_t)(r0 + ty + i*8) * C + c0 + tx];
  __syncthreads();
#pragma unroll
  for (int i = 0; i < 4; ++i)
    out[(size_t)(c0 + ty + i*8) * R + r0 + tx] = (_Float16)tile[tx][ty + i*8];
}

// ---------------- LayerNorm row kernel: f32 in -> f16 out ----------------
__global__ __launch_bounds__(256) void ln_row(const float* __restrict__ x,
                                              const float* __restrict__ g,
                                              const float* __restrict__ bta,
                                              _Float16* __restrict__ out) {
  const int row = blockIdx.x;
  const float4 v = ((const float4*)(x + (size_t)row * Cn))[threadIdx.x];
  float s  = v.x + v.y + v.z + v.w;
  float ss = v.x*v.x + v.y*v.y + v.z*v.z + v.w*v.w;
#pragma unroll
  for (int m = 1; m < 64; m <<= 1) { s += __shfl_xor(s, m); ss += __shfl_xor(ss, m); }
  __shared__ float red[8];
  const int wave = threadIdx.x >> 6, lane = threadIdx.x & 63;
  if (lane == 0) { red[wave] = s; red[4 + wave] = ss; }
  __syncthreads();
  s  = red[0] + red[1] + red[2] + red[3];
  ss = red[4] + red[5] + red[6] + red[7];
  const float mean = s * (1.0f/Cn);
  const float var  = ss * (1.0f/Cn) - mean*mean;
  const float rstd = rsqrtf(var + 1e-6f);
  const int c = threadIdx.x * 4;
  const float4 gg = ((const float4*)g)[threadIdx.x];
  const float4 bb = ((const float4*)bta)[threadIdx.x];
  half4v o;
  o[0] = (_Float16)((v.x - mean) * rstd * gg.x + bb.x);
  o[1] = (_Float16)((v.y - mean) * rstd * gg.y + bb.y);
  o[2] = (_Float16)((v.z - mean) * rstd * gg.z + bb.z);
  o[3] = (_Float16)((v.w - mean) * rstd * gg.w + bb.w);
  *((half4v*)(out + (size_t)row * Cn + c)) = o;
}

// ---------------- GEMM v3: 8-phase schedule, BM=256, BK=64, 8 waves ----------------
// C[M,N] = A[M,K]*Bt[N,K]^T. A/B staged in 4-slot k-half rings (256x32 each),
// one (A+B) half staged per p0/p2 phase, counted vmcnt at p1/p3 (never 0 until
// the last k-half). Two raw s_barriers per phase. XOR chunk swizzle both-sides.
enum { EPI_QKV = 0, EPI_PROJ = 2, EPI_FF1 = 3, EPI_FF2 = 4 };

template<int BN, int EPI>
__global__ __launch_bounds__(512, 2) void gemm8p(const _Float16* __restrict__ A,
                                                 const _Float16* __restrict__ Bt,
                                                 void* __restrict__ outp,
                                                 void* __restrict__ out2,   // QKV: k
                                                 void* __restrict__ out3,   // QKV: vt
                                                 const float* __restrict__ bias,
                                                 const float* __restrict__ resid,
                                                 int M, int N, int K, int nxg) {
  constexpr int NF = BN/64;               // N-frags per wave (4 or 2)
  constexpr int BSLOT = BN*32;            // f16 per B slot
  __shared__ __align__(16) _Float16 Ar[4*256*32];
  __shared__ __align__(16) _Float16 Br[4*BSLOT];

  const int tid = threadIdx.x, wave = tid >> 6, lane = tid & 63;
  const int lr = lane & 15, lg = lane >> 4;
  const int sL = (lr & 3) ^ ((lr >> 2) & 3);
  const int laneoff = lr*32 + ((lg ^ sL) * 8);     // f16 offset within a slot

  // bijective XCD swizzle (gridDim.x % 8 == 0 for all our launches)
  int lin = blockIdx.x;
  const int cpx = gridDim.x >> 3;
  lin = (lin & 7) * cpx + (lin >> 3);
  const int bx = lin % nxg, by = lin / nxg;
  const int brow = by * 256, bcol = bx * BN;
  const int wr = wave >> 2, wc = wave & 3;
  const int arow0 = wr * 128;
  const int bcol0 = wc * (BN/4);

  f32x4 acc[8][NF] = {};

  auto STAGE = [&](int st, int kh) {               // one A-half + one B-half
    const int slot = (2*st + kh) & 3;
    const int koff = st*64 + kh*32;
#pragma unroll
    for (int i = 0; i < 2; ++i) {                  // A: 1024 chunks
      const int qc = i*512 + wave*64 + lane;
      const int row = qc >> 2;
      const int c = (qc & 3) ^ ((row & 3) ^ ((row >> 2) & 3));
      g2l16(A + (size_t)(brow + row)*K + koff + c*8,
            &Ar[slot*8192 + (i*512 + wave*64)*8]);
    }
#pragma unroll
    for (int i = 0; i < BN/128; ++i) {             // B: BN*4 chunks
      const int qc = i*512 + wave*64 + lane;
      const int row = qc >> 2;
      const int c = (qc & 3) ^ ((row & 3) ^ ((row >> 2) & 3));
      g2l16(Bt + (size_t)(bcol + row)*K + koff + c*8,
            &Br[slot*BSLOT + (i*512 + wave*64)*8]);
    }
  };
  auto RDA = [&](int slot, int mh, half8* af) {
#pragma unroll
    for (int i = 0; i < 4; ++i)
      af[i] = *(const half8*)(&Ar[slot*8192 + (arow0 + (mh*4 + i)*16)*32 + laneoff]);
  };
  auto RDB = [&](int slot, half8* bf) {
#pragma unroll
    for (int j = 0; j < NF; ++j)
      bf[j] = *(const half8*)(&Br[slot*BSLOT + (bcol0 + j*16)*32 + laneoff]);
  };

#define MMC(MH) do {                                                          \
    __builtin_amdgcn_s_setprio(1);                                            \
    _Pragma("unroll") for (int i_ = 0; i_ < 4; ++i_)                          \
      _Pragma("unroll") for (int j_ = 0; j_ < NF; ++j_)                       \
        acc[(MH)*4 + i_][j_] = __builtin_amdgcn_mfma_f32_16x16x32_f16(        \
            af[i_], bf[j_], acc[(MH)*4 + i_][j_], 0, 0, 0);                   \
    __builtin_amdgcn_s_setprio(0); } while (0)

  const int ns = K >> 6;                           // >= 3 always here
  STAGE(0, 0); STAGE(0, 1); STAGE(1, 0);
  if constexpr (BN == 256) VMW8; else VMW6;
  SB; BAR;

  half8 af[4], bf[NF];
  for (int s = 0; s < ns - 2; ++s) {
    const int s0 = (2*s) & 3, s1 = s0 + 1;
    // p0
    RDB(s0, bf); RDA(s0, 0, af); STAGE(s + 1, 1);
    SB; BAR; MMC(0); SB; BAR;
    // p1
    RDA(s0, 1, af);
    if constexpr (BN == 256) VMW8; else VMW6;
    SB; BAR; MMC(1); SB; BAR;
    // p2
    RDB(s1, bf); RDA(s1, 0, af); STAGE(s + 2, 0);
    SB; BAR; MMC(0); SB; BAR;
    // p3
    RDA(s1, 1, af);
    if constexpr (BN == 256) VMW8; else VMW6;
    SB; BAR; MMC(1); SB; BAR;
  }
  { // step ns-2: stage only (ns-1,kh1)
    const int s = ns - 2; const int s0 = (2*s) & 3, s1 = s0 + 1;
    RDB(s0, bf); RDA(s0, 0, af); STAGE(s + 1, 1);
    SB; BAR; MMC(0); SB; BAR;
    RDA(s0, 1, af);
    if constexpr (BN == 256) VMW8; else VMW6;
    SB; BAR; MMC(1); SB; BAR;
    RDB(s1, bf); RDA(s1, 0, af);
    SB; BAR; MMC(0); SB; BAR;
    RDA(s1, 1, af);
    if constexpr (BN == 256) VMW4; else VMW3;
    SB; BAR; MMC(1); SB; BAR;
  }
  { // step ns-1: no staging; final drain at p1
    const int s = ns - 1; const int s0 = (2*s) & 3, s1 = s0 + 1;
    RDB(s0, bf); RDA(s0, 0, af);
    SB; BAR; MMC(0); SB; BAR;
    RDA(s0, 1, af);
    VMW0;
    SB; BAR; MMC(1); SB; BAR;
    RDB(s1, bf); RDA(s1, 0, af);
    SB; BAR; MMC(0); SB; BAR;
    RDA(s1, 1, af);
    SB; BAR; MMC(1); SB; BAR;
  }
#undef MMC

  // C/D frag: col = lane&15, row = (lane>>4)*4 + r
#pragma unroll
  for (int a = 0; a < 8; ++a) {
#pragma unroll
    for (int j = 0; j < NF; ++j) {
      const int col = bcol + bcol0 + j*16 + lr;
#pragma unroll
      for (int r = 0; r < 4; ++r) {
        const int row = brow + arow0 + a*16 + lg*4 + r;
        const float v = acc[a][j][r];
        if constexpr (EPI == EPI_QKV) {
          const int sel = col >> 10;            // 0:q 1:k 2:v
          const int cw = col & 1023;
          const int hh = cw >> 6, dd = cw & 63;
          const size_t bhh = (size_t)(row >> 11) * Hn + hh;
          const int t = row & 2047;
          if (sel == 0)      ((_Float16*)outp)[(bhh*Tn + t)*Dn + dd] = (_Float16)v;
          else if (sel == 1) ((_Float16*)out2)[(bhh*Tn + t)*Dn + dd] = (_Float16)v;
          else               ((_Float16*)out3)[(bhh*Dn + dd)*Tn + t] = (_Float16)v;
        } else if constexpr (EPI == EPI_PROJ || EPI == EPI_FF2) {
          ((float*)outp)[(size_t)row * N + col] = v + bias[col] + resid[(size_t)row * N + col];
        } else if constexpr (EPI == EPI_FF1) {
          const float t = v + bias[col];
          ((_Float16*)outp)[(size_t)row * N + col] = (_Float16)(t > 0.f ? t : 0.f);
        }
      }
    }
  }
}

// ---------------- Flash attention (causal), paired q-tiles, KVBLK=64 ----------------
// Swapped-QK^T; in-register softmax; P redistributed via shuffles (no P LDS).
__global__ __launch_bounds__(256) void attn_kernel(const _Float16* __restrict__ q,
                                                   const _Float16* __restrict__ k,
                                                   const _Float16* __restrict__ vt,
                                                   _Float16* __restrict__ out) {
  const int pi = blockIdx.x;                 // 0..7
  const int qtA = pi * 128;
  const int qtB = (15 - pi) * 128;
  const int h = blockIdx.y, b = blockIdx.z;
  const int tid = threadIdx.x, wave = tid >> 6, lane = tid & 63;
  const int lr = lane & 15, lg = lane >> 4;
  const size_t bh = (size_t)b * Hn + h;
  const _Float16* qg = q  + bh * (Tn * Dn);
  const _Float16* kg = k  + bh * (Tn * Dn);
  const _Float16* vg = vt + bh * (Dn * Tn);

  __shared__ __align__(16) _Float16 Ks[2][64*64];
  __shared__ __align__(16) _Float16 Vs[2][64*64];

  const _Float16 qsc = (_Float16)0.03125f;   // C^-0.5 = 2^-5, exact in f16
  half8 qfA[2][2], qfB[2][2];
#pragma unroll
  for (int qi = 0; qi < 2; ++qi)
#pragma unroll
    for (int dh = 0; dh < 2; ++dh) {
      half8 a = *(const half8*)(qg + (size_t)(qtA + wave*32 + qi*16 + lr)*Dn + dh*32 + lg*8);
      half8 c = *(const half8*)(qg + (size_t)(qtB + wave*32 + qi*16 + lr)*Dn + dh*32 + lg*8);
#pragma unroll
      for (int j = 0; j < 8; ++j) { a[j] *= qsc; c[j] *= qsc; }
      qfA[qi][dh] = a; qfB[qi][dh] = c;
    }

  f32x4 oaccA[2][4] = {}, oaccB[2][4] = {};
  float mrowA[2] = {-__builtin_inff(), -__builtin_inff()};
  float mrowB[2] = {-__builtin_inff(), -__builtin_inff()};
  float lsumA[2] = {0.f, 0.f}, lsumB[2] = {0.f, 0.f};

  const int ntB = (qtB >> 6) + 2;

  auto STAGE = [&](int bufi, int t) {
    const int kvt = t * 64;
#pragma unroll
    for (int r = 0; r < 2; ++r) {
      const int g0 = r*256 + wave*64;
      const int g  = g0 + lane;
      const int rr = g >> 3;
      const int cs = (g & 7) ^ (rr & 7);
      g2l16(kg + (size_t)(kvt + rr)*Dn + cs*8, &Ks[bufi][g0*8]);
      g2l16(vg + (size_t)rr*Tn + kvt + cs*8,   &Vs[bufi][g0*8]);
    }
  };

  auto COMPUTE = [&](const half8 (&qf)[2][2], f32x4 (&oacc)[2][4],
                     float* mrow, float* lsum, int qb,
                     const _Float16* KS, const _Float16* VS, int kvt) {
    half8 kb[4][2];
#pragma unroll
    for (int f = 0; f < 4; ++f)
#pragma unroll
      for (int dh = 0; dh < 2; ++dh)
        kb[f][dh] = *(const half8*)(KS + (16*f + lr)*64 + (((4*dh + lg) ^ (lr & 7)) * 8));

#pragma unroll
    for (int qi = 0; qi < 2; ++qi) {
      f32x4 sv[4];
#pragma unroll
      for (int f = 0; f < 4; ++f) {
        f32x4 tacc = {0.f, 0.f, 0.f, 0.f};
        tacc = __builtin_amdgcn_mfma_f32_16x16x32_f16(kb[f][0], qf[qi][0], tacc, 0, 0, 0);
        tacc = __builtin_amdgcn_mfma_f32_16x16x32_f16(kb[f][1], qf[qi][1], tacc, 0, 0, 0);
        sv[f] = tacc;
      }
      const int qrow = qb + wave*32 + qi*16 + lr;
#pragma unroll
      for (int f = 0; f < 4; ++f)
#pragma unroll
        for (int r = 0; r < 4; ++r) {
          const int kvv = kvt + 16*f + 4*lg + r;
          sv[f][r] = (kvv > qrow) ? -__builtin_inff() : sv[f][r];
        }
      float tm = sv[0][0];
#pragma unroll
      for (int f = 0; f < 4; ++f)
#pragma unroll
        for (int r = 0; r < 4; ++r) tm = fmaxf(tm, sv[f][r]);
      tm = fmaxf(tm, __shfl_xor(tm, 16));
      tm = fmaxf(tm, __shfl_xor(tm, 32));
      const float mn = fmaxf(mrow[qi], tm);
      const float alpha = __expf(mrow[qi] - mn);
      mrow[qi] = mn;
      float ps = 0.f;
#pragma unroll
      for (int f = 0; f < 4; ++f)
#pragma unroll
        for (int r = 0; r < 4; ++r) {
          const float e = __expf(sv[f][r] - mn);
          ps += e;
          sv[f][r] = e;
        }
      ps += __shfl_xor(ps, 16);
      ps += __shfl_xor(ps, 32);
      lsum[qi] = lsum[qi] * alpha + ps;
      unsigned ph[4][2];
#pragma unroll
      for (int f = 0; f < 4; ++f)
#pragma unroll
        for (int m = 0; m < 2; ++m) {
          const unsigned lo = (unsigned)__builtin_bit_cast(unsigned short, (_Float16)sv[f][2*m]);
          const unsigned hi = (unsigned)__builtin_bit_cast(unsigned short, (_Float16)sv[f][2*m + 1]);
          ph[f][m] = lo | (hi << 16);
        }
      float ab[4];
#pragma unroll
      for (int r = 0; r < 4; ++r) ab[r] = __shfl(alpha, 4*lg + r);
#pragma unroll
      for (int df = 0; df < 4; ++df)
#pragma unroll
        for (int r = 0; r < 4; ++r) oacc[qi][df][r] *= ab[r];
      const int s0 = lr + 16*(2*(lg & 1));
      const int s1 = s0 + 16;
      half8 pa[2];
#pragma unroll
      for (int kh = 0; kh < 2; ++kh) {
        u32x4 w = {0u, 0u, 0u, 0u};
#pragma unroll
        for (int fi = 0; fi < 2; ++fi) {
          const unsigned a0 = __shfl(ph[2*kh + fi][0], s0);
          const unsigned a1 = __shfl(ph[2*kh + fi][1], s0);
          const unsigned a2 = __shfl(ph[2*kh + fi][0], s1);
          const unsigned a3 = __shfl(ph[2*kh + fi][1], s1);
          const bool sel = ((lg >> 1) == fi);
          w[0] = sel ? a0 : w[0];
          w[1] = sel ? a1 : w[1];
          w[2] = sel ? a2 : w[2];
          w[3] = sel ? a3 : w[3];
        }
        pa[kh] = __builtin_bit_cast(half8, w);
      }
#pragma unroll
      for (int df = 0; df < 4; ++df) {
        half8 vb0 = *(const half8*)(VS + (16*df + lr)*64 + (((0 + lg) ^ (lr & 7)) * 8));
        half8 vb1 = *(const half8*)(VS + (16*df + lr)*64 + (((4 + lg) ^ (lr & 7)) * 8));
        oacc[qi][df] = __builtin_amdgcn_mfma_f32_16x16x32_f16(pa[0], vb0, oacc[qi][df], 0, 0, 0);
        oacc[qi][df] = __builtin_amdgcn_mfma_f32_16x16x32_f16(pa[1], vb1, oacc[qi][df], 0, 0, 0);
      }
    }
  };

  STAGE(0, 0);
  __syncthreads();

  for (int t = 0; t < ntB; ++t) {
    const int kvt = t * 64;
    if (t + 1 < ntB) STAGE((t + 1) & 1, t + 1);
    const _Float16* KS = Ks[t & 1];
    const _Float16* VS = Vs[t & 1];
    if (kvt <= qtA + wave*32 + 31) COMPUTE(qfA, oaccA, mrowA, lsumA, qtA, KS, VS, kvt);
    if (kvt <= qtB + wave*32 + 31) COMPUTE(qfB, oaccB, mrowB, lsumB, qtB, KS, VS, kvt);
    __syncthreads();
  }

  auto EPI = [&](const f32x4 (&oacc)[2][4], const float* lsum, int qb) {
#pragma unroll
    for (int qi = 0; qi < 2; ++qi) {
      const float linv = 1.0f / lsum[qi];
      float lb[4];
#pragma unroll
      for (int r = 0; r < 4; ++r) lb[r] = __shfl(linv, 4*lg + r);
#pragma unroll
      for (int df = 0; df < 4; ++df)
#pragma unroll
        for (int r = 0; r < 4; ++r) {
          const int row = qb + wave*32 + qi*16 + 4*lg + r;
          const int col = h*Dn + df*16 + lr;
          out[((size_t)b*Tn + row)*Cn + col] = (_Float16)(oacc[qi][df][r] * lb[r]);
        }
    }
  };
  EPI(oaccA, lsumA, qtA);
  EPI(oaccB, lsumB, qtB);
}

// ---------------- host launch ----------------
extern "C" void kernel_launch(void* const* d_in, const int* in_sizes, int n_in,
                              void* d_out, int out_size, void* d_ws, size_t ws_size,
                              hipStream_t stream) {
  const float* x      = (const float*)d_in[0];
  const float* wq     = (const float*)d_in[1];
  const float* wk     = (const float*)d_in[2];
  const float* wv     = (const float*)d_in[3];
  const float* w_proj = (const float*)d_in[4];
  const float* b_proj = (const float*)d_in[5];
  const float* w_ff1  = (const float*)d_in[6];
  const float* b_ff1  = (const float*)d_in[7];
  const float* w_ff2  = (const float*)d_in[8];
  const float* b_ff2  = (const float*)d_in[9];
  const float* ln1s   = (const float*)d_in[10];
  const float* ln1b   = (const float*)d_in[11];
  const float* ln2s   = (const float*)d_in[12];
  const float* ln2b   = (const float*)d_in[13];
  float* outp = (float*)d_out;

  char* ws = (char*)d_ws;
  constexpr size_t MB = (size_t)1 << 20;
  _Float16* Wq_t  = (_Float16*)(ws + 0*MB);    // [1024][1024]; Wq/Wk/Wv contiguous =
  _Float16* Wk_t  = (_Float16*)(ws + 2*MB);    //   fused QKV B^T [3072][1024]
  _Float16* Wv_t  = (_Float16*)(ws + 4*MB);
  _Float16* Wp_t  = (_Float16*)(ws + 6*MB);
  _Float16* Wf1_t = (_Float16*)(ws + 8*MB);    // [4096][1024]
  _Float16* Wf2_t = (_Float16*)(ws + 16*MB);   // [1024][4096]
  _Float16* xn    = (_Float16*)(ws + 24*MB);   // [8192][1024]; reused as attn_out
  _Float16* attn_o= (_Float16*)(ws + 24*MB);
  _Float16* qbuf  = (_Float16*)(ws + 40*MB);   // [b][h][t][d]
  _Float16* kbuf  = (_Float16*)(ws + 56*MB);
  _Float16* vtbuf = (_Float16*)(ws + 72*MB);   // [b][h][d][t]
  _Float16* hbuf  = (_Float16*)(ws + 40*MB);   // [8192][4096]; overlays q/k/vt (dead by FF1)
  float*    x2    = (float*)   (ws + 104*MB);  // [8192][1024] f32
  _Float16* xn2   = (_Float16*)(ws + 136*MB);  // [8192][1024]

  dim3 tb(32, 8);
  transpose_f32_f16<<<dim3(2, 32, 16), tb, 0, stream>>>(wq, Wq_t, 1024, 64);
  transpose_f32_f16<<<dim3(2, 32, 16), tb, 0, stream>>>(wk, Wk_t, 1024, 64);
  transpose_f32_f16<<<dim3(2, 32, 16), tb, 0, stream>>>(wv, Wv_t, 1024, 64);
  transpose_f32_f16<<<dim3(32, 32, 1), tb, 0, stream>>>(w_proj, Wp_t, 1024, 1024);
  transpose_f32_f16<<<dim3(128, 32, 1), tb, 0, stream>>>(w_ff1, Wf1_t, 1024, 4096);
  transpose_f32_f16<<<dim3(32, 128, 1), tb, 0, stream>>>(w_ff2, Wf2_t, 4096, 1024);

  ln_row<<<Mr, 256, 0, stream>>>(x, ln1s, ln1b, xn);

  // fused QKV: N=3072, BN=256 -> 12x32 = 384 wg
  gemm8p<256, EPI_QKV><<<dim3(384), 512, 0, stream>>>(xn, Wq_t, qbuf, kbuf, vtbuf,
                                                      nullptr, nullptr, Mr, 3*Cn, Cn, 12);

  attn_kernel<<<dim3(8, Hn, Bn), 256, 0, stream>>>(qbuf, kbuf, vtbuf, attn_o);

  // proj + residual: N=1024, BN=128 -> 8x32 = 256 wg
  gemm8p<128, EPI_PROJ><<<dim3(256), 512, 0, stream>>>(attn_o, Wp_t, x2, nullptr, nullptr,
                                                       b_proj, x, Mr, Cn, Cn, 8);

  ln_row<<<Mr, 256, 0, stream>>>(x2, ln2s, ln2b, xn2);

  // FF1: N=4096, BN=256 -> 16x32 = 512 wg (2 exact rounds)
  gemm8p<256, EPI_FF1><<<dim3(512), 512, 0, stream>>>(xn2, Wf1_t, hbuf, nullptr, nullptr,
                                                      b_ff1, nullptr, Mr, 4*Cn, Cn, 16);
  // FF2: N=1024, K=4096, BN=128 -> 8x32 = 256 wg
  gemm8p<128, EPI_FF2><<<dim3(256), 512, 0, stream>>>(hbuf, Wf2_t, outp, nullptr, nullptr,
                                                      b_ff2, x2, Mr, Cn, 4*Cn, 8);
}